// Round 6
// baseline (203.797 us; speedup 1.0000x reference)
//
#include <hip/hip_runtime.h>
#include <math.h>

// B=4, H=16, S=2048, D=64 causal attention. fp32 in, fp32 out.
// R12 = R11 + skewed software pipeline: QK(t+1) issues BEFORE softmax(t), so
// next-tile MFMA/ds_reads overlap the serial softmax+PV chain (the measured
// ~2800-cyc/block-step critical path that R9-R11 could not dent).
//  - Triple-buffered K/V tiles (skew needs t, t+1 readable while t+2 stages).
//  - sv ping-pong via 2-step unrolled loop (T+1 always even; static indexing).
//  - Algebra patch: sv(t+1) is built against pre-rescale mc, so a rescale at
//    SM(t) also subtracts mx from the pending sv(t+1) (rescale steps only).
// Carried: fa_prep O(S) bf16 conversion, global_load_lds staging, T2 swizzle,
// log2-domain scores, relative defer-max (mc in MFMA C), v_perm pack,
// v_max3 tree, s_setprio, 2-group (32q) waves, q-tile 128.
// Fallback to R6 kernel if ws_size < 32 MiB.

#define S_LEN 2048
#define D_DIM 64
#define TK 64
#define NHEAD 64
#define MASKV -30000.0f   // causal mask value (always underflows exp2)
#define MINIT 1000.0f     // initial -m_i: sv(tile0) ~ +1000 -> forces rescale
#define DEFER_THR 12.0f   // log2 domain: P bounded by 2^12
#define MNEG -30000.0f    // fallback kernel only
#define LSTR 72           // fallback kernel only
#define PREP_KBLK 4096

typedef __attribute__((ext_vector_type(8))) short bf16x8;
typedef __attribute__((ext_vector_type(4))) float f32x4;

static __device__ __forceinline__ float fast_exp2(float x) {
#if __has_builtin(__builtin_amdgcn_exp2f)
    return __builtin_amdgcn_exp2f(x);   // v_exp_f32: 2^x, large-negative -> 0
#else
    float r;
    asm volatile("v_exp_f32 %0, %1\n\ts_nop 1" : "=v"(r) : "v"(x));
    return r;
#endif
}

// clang fuses nested fmaxf to v_max3_f32 (exact)
static __device__ __forceinline__ float fmax3(float a, float b, float c) {
    return fmaxf(fmaxf(a, b), c);
}

// round-half-up fp32->bf16 pair, packed into one dword (a=low, b=high)
static __device__ __forceinline__ unsigned int pack_bf16(float a, float b) {
    union { float f; unsigned int u; } ca, cb;
    ca.f = a; cb.f = b;
    unsigned int ua = ca.u + 0x8000u;
    unsigned int ub = cb.u + 0x8000u;
    return (ua >> 16) | (ub & 0xFFFF0000u);
}

// same bits as pack_bf16, 3 VALU ops: 2 adds + v_perm_b32 byte select.
static __device__ __forceinline__ unsigned int pack_bf16_fast(float a, float b) {
#if __has_builtin(__builtin_amdgcn_perm)
    union { float f; unsigned int u; } ca, cb;
    ca.f = a; cb.f = b;
    return __builtin_amdgcn_perm(cb.u + 0x8000u, ca.u + 0x8000u, 0x07060302u);
#else
    return pack_bf16(a, b);
#endif
}

typedef const __attribute__((address_space(1))) unsigned int* gas1_t;
typedef __attribute__((address_space(3))) unsigned int* las3_t;
// async global->LDS, 16B per lane. LDS dest is wave-uniform base (+lane*16 in HW).
static __device__ __forceinline__ void stage16(const void* g, void* l) {
    __builtin_amdgcn_global_load_lds((gas1_t)g, (las3_t)l, 16, 0, 0);
}

// ---------------------------------------------------------------------------
// Prep: K -> kb (bf16, row-chunk-swizzled), V -> vb (bf16, transposed,
// tile-major, row-chunk-swizzled). Blocks [0,PREP_KBLK): K. Rest: V.
// ---------------------------------------------------------------------------
__global__ __launch_bounds__(256)
void fa_prep(const float* __restrict__ kg, const float* __restrict__ vg,
             unsigned short* __restrict__ kb, unsigned short* __restrict__ vb)
{
    const int tid = threadIdx.x;
    const int bid = blockIdx.x;
    if (bid < PREP_KBLK) {
        // one 16B chunk (8 d-elems) of one K row per thread
        const int cid = bid * 256 + tid;          // (head*S + kv)*8 + ch
        const int ch  = cid & 7;
        const int row = cid >> 3;                 // head*S + kv
        const int kv  = row & (S_LEN - 1);
        const float4* s = reinterpret_cast<const float4*>(kg + (size_t)row * D_DIM + ch * 8);
        float4 a = s[0], b = s[1];
        uint4 w;
        w.x = pack_bf16(a.x, a.y); w.y = pack_bf16(a.z, a.w);
        w.z = pack_bf16(b.x, b.y); w.w = pack_bf16(b.z, b.w);
        const int dst = ch ^ (kv & 7);            // T2 swizzle
        *reinterpret_cast<uint4*>(kb + (size_t)row * D_DIM + dst * 8) = w;
    } else {
        // one 64x64 V tile per wave; lane = (kv-group kg8, d-group dg)
        const int wv   = (bid - PREP_KBLK) * 4 + (tid >> 6);  // head*32 + t
        const int lane = tid & 63;
        const int kg8  = lane >> 3;
        const int dg   = lane & 7;
        const float* s = vg + ((size_t)wv * TK + kg8 * 8) * D_DIM + dg * 8;
        float va[8][8];                            // [kv in group][d in group]
        #pragma unroll
        for (int i = 0; i < 8; ++i) {
            const float4* sp = reinterpret_cast<const float4*>(s + (size_t)i * D_DIM);
            float4 x = sp[0], y = sp[1];
            va[i][0] = x.x; va[i][1] = x.y; va[i][2] = x.z; va[i][3] = x.w;
            va[i][4] = y.x; va[i][5] = y.y; va[i][6] = y.z; va[i][7] = y.w;
        }
        unsigned short* db = vb + (size_t)wv * (TK * D_DIM);  // tile base (8 KB)
        #pragma unroll
        for (int j = 0; j < 8; ++j) {
            const int d = dg * 8 + j;             // d&7 == j
            uint4 w;
            w.x = pack_bf16(va[0][j], va[1][j]);
            w.y = pack_bf16(va[2][j], va[3][j]);
            w.z = pack_bf16(va[4][j], va[5][j]);
            w.w = pack_bf16(va[6][j], va[7][j]);
            *reinterpret_cast<uint4*>(db + d * D_DIM + 8 * (kg8 ^ j)) = w;
        }
    }
}

// ---- stage tile TI (K+V) into buffer TI%3 (4 global_load_lds per wave)
#define STAGE(TI)                                                              \
    {                                                                          \
        const int b_ = (TI) % 3;                                               \
        const unsigned short* ks_ = kbh + (size_t)(TI) * 4096 + sgo;           \
        const unsigned short* vs_ = vbh + (size_t)(TI) * 4096 + sgo;           \
        char* kd_ = klds + b_ * 8192 + wave * 1024;                            \
        char* vd_ = vlds + b_ * 8192 + wave * 1024;                            \
        stage16(ks_,        kd_);                                              \
        stage16(ks_ + 2048, kd_ + 4096);                                       \
        stage16(vs_,        vd_);                                              \
        stage16(vs_ + 2048, vd_ + 4096);                                       \
    }

// ---- S^T = K·Q^T + (-m) for both groups from buffer BUFI
#define QK_TILE(BUFI, SVA, SVB)                                                \
    {                                                                          \
        const char* kt_ = klds + (BUFI) * 8192;                                \
        __builtin_amdgcn_s_setprio(1);                                         \
        _Pragma("unroll")                                                      \
        for (int nt = 0; nt < 4; ++nt) {                                       \
            const char* kr_ = kt_ + nt * 2048 + rowB;                          \
            bf16x8 kf0 = *reinterpret_cast<const bf16x8*>(kr_ + colA);         \
            bf16x8 kf1 = *reinterpret_cast<const bf16x8*>(kr_ + colB);         \
            f32x4 aA = __builtin_amdgcn_mfma_f32_16x16x32_bf16(kf0, qfA[0], mcA, 0, 0, 0); \
            aA = __builtin_amdgcn_mfma_f32_16x16x32_bf16(kf1, qfA[1], aA, 0, 0, 0);        \
            f32x4 aB = __builtin_amdgcn_mfma_f32_16x16x32_bf16(kf0, qfB[0], mcB, 0, 0, 0); \
            aB = __builtin_amdgcn_mfma_f32_16x16x32_bf16(kf1, qfB[1], aB, 0, 0, 0);        \
            _Pragma("unroll")                                                  \
            for (int r = 0; r < 4; ++r) { SVA[nt][r] = aA[r]; SVB[nt][r] = aB[r]; } \
        }                                                                      \
        __builtin_amdgcn_s_setprio(0);                                         \
    }

// ---- causal masks for kv-tile U. Group A diagonal at U==T-1, dead at U==T
// (shift form); group B diagonal at U==T.
#define MASK_TILES(U, SVA, SVB)                                                \
    {                                                                          \
        if ((U) >= T - 1) {                                                    \
            const int sh_ = ((U) - (T - 1)) << 6;                              \
            _Pragma("unroll")                                                  \
            for (int nt = 0; nt < 4; ++nt)                                     \
                _Pragma("unroll")                                              \
                for (int r = 0; r < 4; ++r)                                    \
                    if (sh_ + nt * 16 + quad * 4 + r > wave * 16 + m16) SVA[nt][r] = MASKV; \
        }                                                                      \
        if ((U) == T) {                                                        \
            _Pragma("unroll")                                                  \
            for (int nt = 0; nt < 4; ++nt)                                     \
                _Pragma("unroll")                                              \
                for (int r = 0; r < 4; ++r)                                    \
                    if (nt * 16 + quad * 4 + r > wave * 16 + m16) SVB[nt][r] = MASKV; \
        }                                                                      \
    }

// ---- online softmax for one group (relative domain, defer-max). On rescale,
// also shifts the PENDING next-tile scores SVN (built against pre-rescale mc).
#define SOFTMAX_G(SV, SVN, MC, LI, OACC, PL)                                   \
    {                                                                          \
        float x0 = fmax3(SV[0][0], SV[0][1], SV[0][2]);                        \
        float x1 = fmax3(SV[0][3], SV[1][0], SV[1][1]);                        \
        float x2 = fmax3(SV[1][2], SV[1][3], SV[2][0]);                        \
        float x3 = fmax3(SV[2][1], SV[2][2], SV[2][3]);                        \
        float x4 = fmax3(SV[3][0], SV[3][1], SV[3][2]);                        \
        float y0 = fmax3(x0, x1, x2);                                          \
        float y1 = fmax3(x3, x4, SV[3][3]);                                    \
        float rm = fmaxf(y0, y1);                                              \
        rm = fmaxf(rm, __shfl_xor(rm, 16, 64));                                \
        rm = fmaxf(rm, __shfl_xor(rm, 32, 64));                                \
        if (__any(rm > DEFER_THR)) {                                           \
            float mx    = fmaxf(rm, 0.f);                                      \
            float alpha = fast_exp2(-mx);                                      \
            LI *= alpha;                                                       \
            _Pragma("unroll")                                                  \
            for (int nc = 0; nc < 4; ++nc)                                     \
                _Pragma("unroll")                                              \
                for (int r = 0; r < 4; ++r) OACC[nc][r] *= alpha;              \
            _Pragma("unroll")                                                  \
            for (int nt = 0; nt < 4; ++nt)                                     \
                _Pragma("unroll")                                              \
                for (int r = 0; r < 4; ++r) { SV[nt][r] -= mx; SVN[nt][r] -= mx; } \
            _Pragma("unroll")                                                  \
            for (int r = 0; r < 4; ++r) MC[r] -= mx;                           \
        }                                                                      \
        float rs = 0.f;                                                        \
        _Pragma("unroll")                                                      \
        for (int nt = 0; nt < 4; ++nt) {                                       \
            float e0 = fast_exp2(SV[nt][0]);                                   \
            float e1 = fast_exp2(SV[nt][1]);                                   \
            float e2 = fast_exp2(SV[nt][2]);                                   \
            float e3 = fast_exp2(SV[nt][3]);                                   \
            rs += (e0 + e1) + (e2 + e3);                                       \
            uint2 pw;                                                          \
            pw.x = pack_bf16_fast(e0, e1);                                     \
            pw.y = pack_bf16_fast(e2, e3);                                     \
            *reinterpret_cast<uint2*>(PL + ((nt * 32 + quad * 8) ^ swz)) = pw; \
        }                                                                      \
        rs += __shfl_xor(rs, 16, 64);                                          \
        rs += __shfl_xor(rs, 32, 64);                                          \
        LI += rs;                                                              \
    }

// ---- one pipelined step: stage(TT+2) || QK(TT+1)->next || SM(TT) || PV(TT)
#define FA_STEP(TT, SCA, SCB, SNA, SNB)                                        \
    {                                                                          \
        if ((TT) + 2 <= T) STAGE((TT) + 2);                                    \
        if ((TT) + 1 <= T) {                                                   \
            QK_TILE(((TT) + 1) % 3, SNA, SNB);                                 \
            MASK_TILES((TT) + 1, SNA, SNB);                                    \
        }                                                                      \
        SOFTMAX_G(SCA, SNA, mcA, lA, oaccA, plA);                              \
        SOFTMAX_G(SCB, SNB, mcB, lB, oaccB, plB);                              \
        asm volatile("s_waitcnt lgkmcnt(0)" ::: "memory");                     \
        {                                                                      \
            const char* vt_ = vlds + ((TT) % 3) * 8192;                        \
            bf16x8 pfA0 = *reinterpret_cast<const bf16x8*>(plA + colA);        \
            bf16x8 pfA1 = *reinterpret_cast<const bf16x8*>(plA + colB);        \
            bf16x8 pfB0 = *reinterpret_cast<const bf16x8*>(plB + colA);        \
            bf16x8 pfB1 = *reinterpret_cast<const bf16x8*>(plB + colB);        \
            __builtin_amdgcn_s_setprio(1);                                     \
            _Pragma("unroll")                                                  \
            for (int nc = 0; nc < 4; ++nc) {                                   \
                const char* vr_ = vt_ + nc * 2048 + rowB;                      \
                bf16x8 vf0 = *reinterpret_cast<const bf16x8*>(vr_ + colA);     \
                bf16x8 vf1 = *reinterpret_cast<const bf16x8*>(vr_ + colB);     \
                oaccA[nc] = __builtin_amdgcn_mfma_f32_16x16x32_bf16(vf0, pfA0, oaccA[nc], 0, 0, 0); \
                oaccA[nc] = __builtin_amdgcn_mfma_f32_16x16x32_bf16(vf1, pfA1, oaccA[nc], 0, 0, 0); \
                oaccB[nc] = __builtin_amdgcn_mfma_f32_16x16x32_bf16(vf0, pfB0, oaccB[nc], 0, 0, 0); \
                oaccB[nc] = __builtin_amdgcn_mfma_f32_16x16x32_bf16(vf1, pfB1, oaccB[nc], 0, 0, 0); \
            }                                                                  \
            __builtin_amdgcn_s_setprio(0);                                     \
        }                                                                      \
        __syncthreads();                                                       \
    }

// ---------------------------------------------------------------------------
// Main: flash fwd, S^T formulation, bf16 K/V from workspace.
// Q-tile 128 (wave owns 32 q = 2 groups); skewed pipeline, triple-buffer K/V.
// LDS = 3*8K (K) + 3*8K (V) + 16K (P) = 64K -> 2 blocks/CU (grid-capped).
// ---------------------------------------------------------------------------
__global__ __launch_bounds__(256, 2)
void fa_fwd(const float* __restrict__ qg,
            const unsigned short* __restrict__ kb,
            const unsigned short* __restrict__ vb,
            float* __restrict__ og)
{
    const int head = blockIdx.x;          // fast dim -> XCD spread
    const int pr   = blockIdx.y;          // 0..7: q-tile pairs {pr, 15-pr}
    const int tid  = threadIdx.x;
    const int wave = tid >> 6;
    const int lane = tid & 63;
    const int m16  = lane & 15;
    const int quad = lane >> 4;

    __shared__ unsigned short Kl[3][TK * D_DIM];     // swizzled [kv][d] bf16
    __shared__ unsigned short Vt[3][TK * D_DIM];     // swizzled [d][kv] bf16
    __shared__ unsigned short Pl[4][2][16 * TK];     // per-wave, per-group P

    const size_t hoff = (size_t)head * S_LEN * D_DIM;
    const unsigned short* kbh = kb + hoff;
    const unsigned short* vbh = vb + hoff;
    float* __restrict__ ogh = og + hoff;

    // swizzled byte columns within a 128B row (row&7 == m16&7 for all rows used)
    const int swz  = (m16 & 7) << 4;
    const int colA = (quad * 16) ^ swz;
    const int colB = (64 + quad * 16) ^ swz;
    const int rowB = m16 * 128;
    const int sgo  = wave * 512 + lane * 8;   // staging src offset (shorts)

    char* klds = (char*)&Kl[0][0];
    char* vlds = (char*)&Vt[0][0];
    char* plA  = (char*)&Pl[0][0][0] + wave * 4096 + m16 * 128;
    char* plB  = plA + 2048;

    const float QSC = 0.18033688011112042f;   // 1/8 * log2(e): log2-domain scores

    for (int pass = 0; pass < 2; ++pass) {
        const int idx = (pass == 0) ? pr : (15 - pr);
        const int q0  = idx * 128;
        const int T   = (q0 >> 6) + 1;        // last kv-tile (odd; T+1 even)

        // ---- Q fragments (B operand): group A rows q0+wave*16+m16, B +64
        bf16x8 qfA[2], qfB[2];
        {
            const float* qpA = qg + hoff + (size_t)(q0 + wave * 16 + m16) * D_DIM + quad * 8;
            #pragma unroll
            for (int c = 0; c < 2; ++c) {
                float4 a = reinterpret_cast<const float4*>(qpA + c * 32)[0];
                float4 b = reinterpret_cast<const float4*>(qpA + c * 32)[1];
                unsigned int u0 = pack_bf16(a.x * QSC, a.y * QSC);
                unsigned int u1 = pack_bf16(a.z * QSC, a.w * QSC);
                unsigned int u2 = pack_bf16(b.x * QSC, b.y * QSC);
                unsigned int u3 = pack_bf16(b.z * QSC, b.w * QSC);
                qfA[c][0] = (short)(u0 & 0xFFFF); qfA[c][1] = (short)(u0 >> 16);
                qfA[c][2] = (short)(u1 & 0xFFFF); qfA[c][3] = (short)(u1 >> 16);
                qfA[c][4] = (short)(u2 & 0xFFFF); qfA[c][5] = (short)(u2 >> 16);
                qfA[c][6] = (short)(u3 & 0xFFFF); qfA[c][7] = (short)(u3 >> 16);
            }
            const float* qpB = qpA + 64 * D_DIM;
            #pragma unroll
            for (int c = 0; c < 2; ++c) {
                float4 a = reinterpret_cast<const float4*>(qpB + c * 32)[0];
                float4 b = reinterpret_cast<const float4*>(qpB + c * 32)[1];
                unsigned int u0 = pack_bf16(a.x * QSC, a.y * QSC);
                unsigned int u1 = pack_bf16(a.z * QSC, a.w * QSC);
                unsigned int u2 = pack_bf16(b.x * QSC, b.y * QSC);
                unsigned int u3 = pack_bf16(b.z * QSC, b.w * QSC);
                qfB[c][0] = (short)(u0 & 0xFFFF); qfB[c][1] = (short)(u0 >> 16);
                qfB[c][2] = (short)(u1 & 0xFFFF); qfB[c][3] = (short)(u1 >> 16);
                qfB[c][4] = (short)(u2 & 0xFFFF); qfB[c][5] = (short)(u2 >> 16);
                qfB[c][6] = (short)(u3 & 0xFFFF); qfB[c][7] = (short)(u3 >> 16);
            }
        }

        float lA = 0.f, lB = 0.f;
        f32x4 mcA = (f32x4){MINIT, MINIT, MINIT, MINIT};
        f32x4 mcB = (f32x4){MINIT, MINIT, MINIT, MINIT};
        f32x4 oaccA[4], oaccB[4];
        #pragma unroll
        for (int nc = 0; nc < 4; ++nc) {
            oaccA[nc] = (f32x4){0.f, 0.f, 0.f, 0.f};
            oaccB[nc] = (f32x4){0.f, 0.f, 0.f, 0.f};
        }

        // ---- prologue: tiles 0,1 staged; QK(0) computed before the loop
        STAGE(0)
        STAGE(1)
        __syncthreads();

        float svcA[4][4], svcB[4][4], svnA[4][4], svnB[4][4];
        QK_TILE(0, svcA, svcB)
        MASK_TILES(0, svcA, svcB)

        // ---- main loop, 2-step unrolled ping-pong (T+1 is even)
        for (int t = 0; t <= T; t += 2) {
            FA_STEP(t,     svcA, svcB, svnA, svnB)
            FA_STEP(t + 1, svnA, svnB, svcA, svcB)
        }

        // ---- epilogue: group A row q0+wave*16+m16, group B +64
        {
            float inv = 1.0f / lA;
            float* op = ogh + (size_t)(q0 + wave * 16 + m16) * D_DIM;
            #pragma unroll
            for (int nc = 0; nc < 4; ++nc) {
                float4 o4;
                o4.x = oaccA[nc][0] * inv;
                o4.y = oaccA[nc][1] * inv;
                o4.z = oaccA[nc][2] * inv;
                o4.w = oaccA[nc][3] * inv;
                reinterpret_cast<float4*>(op + nc * 16 + quad * 4)[0] = o4;
            }
        }
        {
            float inv = 1.0f / lB;
            float* op = ogh + (size_t)(q0 + 64 + wave * 16 + m16) * D_DIM;
            #pragma unroll
            for (int nc = 0; nc < 4; ++nc) {
                float4 o4;
                o4.x = oaccB[nc][0] * inv;
                o4.y = oaccB[nc][1] * inv;
                o4.z = oaccB[nc][2] * inv;
                o4.w = oaccB[nc][3] * inv;
                reinterpret_cast<float4*>(op + nc * 16 + quad * 4)[0] = o4;
            }
        }
    }
}

// ---------------------------------------------------------------------------
// Fallback (R6 kernel, verbatim) — used only if ws_size < 32 MiB.
// ---------------------------------------------------------------------------
__global__ __launch_bounds__(256, 4)
void fa_fwd_fb(const float* __restrict__ qg,
               const float* __restrict__ kg,
               const float* __restrict__ vg,
               float* __restrict__ og)
{
    const int head = blockIdx.x;
    const int pr   = blockIdx.y;
    const int tid  = threadIdx.x;
    const int wave = tid >> 6;
    const int lane = tid & 63;
    const int m16  = lane & 15;
    const int quad = lane >> 4;

    __shared__ unsigned short Kl[TK][LSTR];
    __shared__ unsigned short Vt[D_DIM][LSTR];
    __shared__ unsigned short Pl[4][16][LSTR];

    const size_t hoff = (size_t)head * S_LEN * D_DIM;
    const float* kh = kg + hoff;
    const float* vh = vg + hoff;

    const int ksr = tid >> 2;
    const int ksc = (tid & 3) << 4;
    const int va  = lane >> 3;
    const int vb  = lane & 7;
    const int vrr = wave * 16 + 2 * vb;
    const int vcc = 8 * va;
    const float LOG2E = 1.4426950408889634f;

    for (int pass = 0; pass < 2; ++pass) {
        const int q0 = ((pass == 0) ? pr : (31 - pr)) * TK;

        bf16x8 qf[2];
        {
            const float* qp = qg + hoff + (size_t)(q0 + wave * 16 + m16) * D_DIM + quad * 8;
            #pragma unroll
            for (int c = 0; c < 2; ++c) {
                float4 a = reinterpret_cast<const float4*>(qp + c * 32)[0];
                float4 b = reinterpret_cast<const float4*>(qp + c * 32)[1];
                unsigned int u0 = pack_bf16(a.x * 0.125f, a.y * 0.125f);
                unsigned int u1 = pack_bf16(a.z * 0.125f, a.w * 0.125f);
                unsigned int u2 = pack_bf16(b.x * 0.125f, b.y * 0.125f);
                unsigned int u3 = pack_bf16(b.z * 0.125f, b.w * 0.125f);
                qf[c][0] = (short)(u0 & 0xFFFF); qf[c][1] = (short)(u0 >> 16);
                qf[c][2] = (short)(u1 & 0xFFFF); qf[c][3] = (short)(u1 >> 16);
                qf[c][4] = (short)(u2 & 0xFFFF); qf[c][5] = (short)(u2 >> 16);
                qf[c][6] = (short)(u3 & 0xFFFF); qf[c][7] = (short)(u3 >> 16);
            }
        }

        float m_i = MNEG, l_i = 0.f;
        f32x4 oacc[4];
        #pragma unroll
        for (int nc = 0; nc < 4; ++nc) oacc[nc] = (f32x4){0.f, 0.f, 0.f, 0.f};

        float4 kA, kB, kC, kD, vA, vB, vC, vD;
        {
            const float* kp = kh + (size_t)ksr * D_DIM + ksc;
            kA = reinterpret_cast<const float4*>(kp)[0];
            kB = reinterpret_cast<const float4*>(kp)[1];
            kC = reinterpret_cast<const float4*>(kp)[2];
            kD = reinterpret_cast<const float4*>(kp)[3];
            const float* vp = vh + (size_t)vrr * D_DIM + vcc;
            vA = reinterpret_cast<const float4*>(vp)[0];
            vB = reinterpret_cast<const float4*>(vp)[1];
            vC = reinterpret_cast<const float4*>(vp + D_DIM)[0];
            vD = reinterpret_cast<const float4*>(vp + D_DIM)[1];
        }

        for (int j0 = 0; j0 <= q0; j0 += TK) {
            __syncthreads();
            {
                uint4 w0, w1;
                w0.x = pack_bf16(kA.x, kA.y); w0.y = pack_bf16(kA.z, kA.w);
                w0.z = pack_bf16(kB.x, kB.y); w0.w = pack_bf16(kB.z, kB.w);
                w1.x = pack_bf16(kC.x, kC.y); w1.y = pack_bf16(kC.z, kC.w);
                w1.z = pack_bf16(kD.x, kD.y); w1.w = pack_bf16(kD.z, kD.w);
                *reinterpret_cast<uint4*>(&Kl[ksr][ksc])     = w0;
                *reinterpret_cast<uint4*>(&Kl[ksr][ksc + 8]) = w1;

                float r0[8] = {vA.x, vA.y, vA.z, vA.w, vB.x, vB.y, vB.z, vB.w};
                float r1[8] = {vC.x, vC.y, vC.z, vC.w, vD.x, vD.y, vD.z, vD.w};
                #pragma unroll
                for (int jj = 0; jj < 8; ++jj) {
                    int j = (jj + va) & 7;
                    *reinterpret_cast<unsigned int*>(&Vt[vcc + j][vrr]) = pack_bf16(r0[j], r1[j]);
                }
            }
            __syncthreads();

            if (j0 + TK <= q0) {
                const float* kp = kh + (size_t)(j0 + TK + ksr) * D_DIM + ksc;
                kA = reinterpret_cast<const float4*>(kp)[0];
                kB = reinterpret_cast<const float4*>(kp)[1];
                kC = reinterpret_cast<const float4*>(kp)[2];
                kD = reinterpret_cast<const float4*>(kp)[3];
                const float* vp = vh + (size_t)(j0 + TK + vrr) * D_DIM + vcc;
                vA = reinterpret_cast<const float4*>(vp)[0];
                vB = reinterpret_cast<const float4*>(vp)[1];
                vC = reinterpret_cast<const float4*>(vp + D_DIM)[0];
                vD = reinterpret_cast<const float4*>(vp + D_DIM)[1];
            }

            float sv[4][4];
            #pragma unroll
            for (int nt = 0; nt < 4; ++nt) {
                f32x4 acc = (f32x4){0.f, 0.f, 0.f, 0.f};
                bf16x8 kf0 = *reinterpret_cast<const bf16x8*>(&Kl[nt * 16 + m16][quad * 8]);
                bf16x8 kf1 = *reinterpret_cast<const bf16x8*>(&Kl[nt * 16 + m16][32 + quad * 8]);
                acc = __builtin_amdgcn_mfma_f32_16x16x32_bf16(kf0, qf[0], acc, 0, 0, 0);
                acc = __builtin_amdgcn_mfma_f32_16x16x32_bf16(kf1, qf[1], acc, 0, 0, 0);
                #pragma unroll
                for (int r = 0; r < 4; ++r) sv[nt][r] = acc[r];
            }

            if (j0 == q0) {
                #pragma unroll
                for (int nt = 0; nt < 4; ++nt)
                    #pragma unroll
                    for (int r = 0; r < 4; ++r)
                        if (nt * 16 + quad * 4 + r > wave * 16 + m16) sv[nt][r] = MNEG;
            }

            float a0 = fmaxf(fmaxf(sv[0][0], sv[0][1]), fmaxf(sv[0][2], sv[0][3]));
            float a1 = fmaxf(fmaxf(sv[1][0], sv[1][1]), fmaxf(sv[1][2], sv[1][3]));
            float a2 = fmaxf(fmaxf(sv[2][0], sv[2][1]), fmaxf(sv[2][2], sv[2][3]));
            float a3 = fmaxf(fmaxf(sv[3][0], sv[3][1]), fmaxf(sv[3][2], sv[3][3]));
            float rm = fmaxf(fmaxf(a0, a1), fmaxf(a2, a3));
            rm = fmaxf(rm, __shfl_xor(rm, 16, 64));
            rm = fmaxf(rm, __shfl_xor(rm, 32, 64));
            float mnew  = fmaxf(m_i, rm);
            float alpha = fast_exp2((m_i - mnew) * LOG2E);
            float msc   = mnew * LOG2E;
            m_i = mnew;

            float rs = 0.f;
            #pragma unroll
            for (int nt = 0; nt < 4; ++nt) {
                float e0 = fast_exp2(fmaf(sv[nt][0], LOG2E, -msc));
                float e1 = fast_exp2(fmaf(sv[nt][1], LOG2E, -msc));
                float e2 = fast_exp2(fmaf(sv[nt][2], LOG2E, -msc));
                float e3 = fast_exp2(fmaf(sv[nt][3], LOG2E, -msc));
                rs += (e0 + e1) + (e2 + e3);
                uint2 pw;
                pw.x = pack_bf16(e0, e1);
                pw.y = pack_bf16(e2, e3);
                *reinterpret_cast<uint2*>(&Pl[wave][m16][nt * 16 + quad * 4]) = pw;
            }
            rs += __shfl_xor(rs, 16, 64);
            rs += __shfl_xor(rs, 32, 64);
            l_i = fmaf(alpha, l_i, rs);

            #pragma unroll
            for (int nc = 0; nc < 4; ++nc)
                #pragma unroll
                for (int r = 0; r < 4; ++r)
                    oacc[nc][r] *= alpha;

            asm volatile("s_waitcnt lgkmcnt(0)" ::: "memory");

            bf16x8 pf0 = *reinterpret_cast<const bf16x8*>(&Pl[wave][m16][quad * 8]);
            bf16x8 pf1 = *reinterpret_cast<const bf16x8*>(&Pl[wave][m16][32 + quad * 8]);
            #pragma unroll
            for (int nc = 0; nc < 4; ++nc) {
                bf16x8 vf0 = *reinterpret_cast<const bf16x8*>(&Vt[nc * 16 + m16][quad * 8]);
                bf16x8 vf1 = *reinterpret_cast<const bf16x8*>(&Vt[nc * 16 + m16][32 + quad * 8]);
                oacc[nc] = __builtin_amdgcn_mfma_f32_16x16x32_bf16(vf0, pf0, oacc[nc], 0, 0, 0);
                oacc[nc] = __builtin_amdgcn_mfma_f32_16x16x32_bf16(vf1, pf1, oacc[nc], 0, 0, 0);
            }
        }

        float inv = 1.0f / l_i;
        float* op = og + hoff + (size_t)(q0 + wave * 16 + m16) * D_DIM;
        #pragma unroll
        for (int nc = 0; nc < 4; ++nc) {
            float4 o4;
            o4.x = oacc[nc][0] * inv;
            o4.y = oacc[nc][1] * inv;
            o4.z = oacc[nc][2] * inv;
            o4.w = oacc[nc][3] * inv;
            reinterpret_cast<float4*>(op + nc * 16 + quad * 4)[0] = o4;
        }
    }
}

extern "C" void kernel_launch(void* const* d_in, const int* in_sizes, int n_in,
                              void* d_out, int out_size, void* d_ws, size_t ws_size,
                              hipStream_t stream) {
    const float* q = (const float*)d_in[0];
    const float* k = (const float*)d_in[1];
    const float* v = (const float*)d_in[2];
    float* o = (float*)d_out;
    const size_t kvShorts = (size_t)NHEAD * S_LEN * D_DIM;           // 8.39M
    const size_t wsNeed   = 2 * kvShorts * sizeof(unsigned short);   // 32 MiB
    if (d_ws != nullptr && ws_size >= wsNeed) {
        unsigned short* kb = (unsigned short*)d_ws;
        unsigned short* vb = kb + kvShorts;
        fa_prep<<<PREP_KBLK + 512, 256, 0, stream>>>(k, v, kb, vb);
        dim3 grid(NHEAD, 8);
        fa_fwd<<<grid, 256, 0, stream>>>(q, kb, vb, o);
    } else {
        dim3 grid(NHEAD, 16);
        fa_fwd_fb<<<grid, 256, 0, stream>>>(q, k, v, o);
    }
}

// Round 7
// 200.165 us; speedup vs baseline: 1.0181x; 1.0181x over previous
//
#include <hip/hip_runtime.h>
#include <math.h>

// B=4, H=16, S=2048, D=64 causal attention. fp32 in, fp32 out.
// R13 = R11 fwd (verbatim; equal-best 80.2us) + throughput-restructured prep.
// Residual analysis: dur - fwd = 84.6us without prep (R6), ~120us with prep
// (R8-R12) -> prep ~35us vs ~15us traffic floor. Old prep: 4608 blocks, one
// 32B-load/16B-store per K thread (no ILP). New prep: K = 1024 blocks x 4
// chunks/thread (8 loads/4 stores in flight); V = 128 blocks x 4 tiles/wave
// grid-stride. Output bytes identical.
// fwd carried: 2-group (32q) waves, q-tile 128, fa_prep O(S) bf16 conversion,
// global_load_lds staging, dbuf, T2 swizzle, log2-domain scores, relative
// defer-max (mc in MFMA C), v_perm pack, v_max3 tree, s_setprio.
// Fallback to R6 kernel if ws_size < 32 MiB.

#define S_LEN 2048
#define D_DIM 64
#define TK 64
#define NHEAD 64
#define MASKV -30000.0f   // causal mask value (always underflows exp2)
#define MINIT 1000.0f     // initial -m_i: sv(tile0) ~ +1000 -> forces rescale
#define DEFER_THR 12.0f   // log2 domain: P bounded by 2^12
#define MNEG -30000.0f    // fallback kernel only
#define LSTR 72           // fallback kernel only
#define PREP_KBLK 1024    // K-branch blocks (x4 chunks/thread)
#define PREP_VBLK 128     // V-branch blocks (x4 tiles/wave)

typedef __attribute__((ext_vector_type(8))) short bf16x8;
typedef __attribute__((ext_vector_type(4))) float f32x4;

static __device__ __forceinline__ float fast_exp2(float x) {
#if __has_builtin(__builtin_amdgcn_exp2f)
    return __builtin_amdgcn_exp2f(x);   // v_exp_f32: 2^x, large-negative -> 0
#else
    float r;
    asm volatile("v_exp_f32 %0, %1\n\ts_nop 1" : "=v"(r) : "v"(x));
    return r;
#endif
}

// clang fuses nested fmaxf to v_max3_f32 (exact)
static __device__ __forceinline__ float fmax3(float a, float b, float c) {
    return fmaxf(fmaxf(a, b), c);
}

// round-half-up fp32->bf16 pair, packed into one dword (a=low, b=high)
static __device__ __forceinline__ unsigned int pack_bf16(float a, float b) {
    union { float f; unsigned int u; } ca, cb;
    ca.f = a; cb.f = b;
    unsigned int ua = ca.u + 0x8000u;
    unsigned int ub = cb.u + 0x8000u;
    return (ua >> 16) | (ub & 0xFFFF0000u);
}

// same bits as pack_bf16, 3 VALU ops: 2 adds + v_perm_b32 byte select.
static __device__ __forceinline__ unsigned int pack_bf16_fast(float a, float b) {
#if __has_builtin(__builtin_amdgcn_perm)
    union { float f; unsigned int u; } ca, cb;
    ca.f = a; cb.f = b;
    return __builtin_amdgcn_perm(cb.u + 0x8000u, ca.u + 0x8000u, 0x07060302u);
#else
    return pack_bf16(a, b);
#endif
}

typedef const __attribute__((address_space(1))) unsigned int* gas1_t;
typedef __attribute__((address_space(3))) unsigned int* las3_t;
// async global->LDS, 16B per lane. LDS dest is wave-uniform base (+lane*16 in HW).
static __device__ __forceinline__ void stage16(const void* g, void* l) {
    __builtin_amdgcn_global_load_lds((gas1_t)g, (las3_t)l, 16, 0, 0);
}

// ---------------------------------------------------------------------------
// Prep v2: K -> kb (bf16, row-chunk-swizzled), V -> vb (bf16, transposed,
// tile-major, row-chunk-swizzled). Output bytes identical to prep v1;
// restructured for per-thread ILP (4x work per thread, 4x fewer blocks).
// Blocks [0,PREP_KBLK): K. [PREP_KBLK, PREP_KBLK+PREP_VBLK): V.
// ---------------------------------------------------------------------------
__global__ __launch_bounds__(256)
void fa_prep(const float* __restrict__ kg, const float* __restrict__ vg,
             unsigned short* __restrict__ kb, unsigned short* __restrict__ vb)
{
    const int tid = threadIdx.x;
    const int bid = blockIdx.x;
    if (bid < PREP_KBLK) {
        // 4 x 16B chunks (8 d-elems each) of K rows per thread, strided so
        // each iteration stays wave-coalesced. 1024*256*4 = 1,048,576 chunks.
        const int tcid = bid * 256 + tid;          // 0..262143
        float4 a[4], b[4];
        int rowv[4], dstv[4];
        #pragma unroll
        for (int s = 0; s < 4; ++s) {
            const int cid = tcid + s * 262144;     // (head*S + kv)*8 + ch
            const int ch  = cid & 7;
            const int row = cid >> 3;              // head*S + kv
            const int kv  = row & (S_LEN - 1);
            const float4* sp = reinterpret_cast<const float4*>(kg + (size_t)row * D_DIM + ch * 8);
            a[s] = sp[0];
            b[s] = sp[1];
            rowv[s] = row;
            dstv[s] = ch ^ (kv & 7);               // T2 swizzle
        }
        #pragma unroll
        for (int s = 0; s < 4; ++s) {
            uint4 w;
            w.x = pack_bf16(a[s].x, a[s].y); w.y = pack_bf16(a[s].z, a[s].w);
            w.z = pack_bf16(b[s].x, b[s].y); w.w = pack_bf16(b[s].z, b[s].w);
            *reinterpret_cast<uint4*>(kb + (size_t)rowv[s] * D_DIM + dstv[s] * 8) = w;
        }
    } else {
        // 4 x (64x64 V tile) per wave, grid-stride; lane = (kv-group, d-group)
        const int wvb  = (bid - PREP_KBLK) * 4 + (tid >> 6);  // 0..511
        const int lane = tid & 63;
        const int kg8  = lane >> 3;
        const int dg   = lane & 7;
        #pragma unroll 1
        for (int s = 0; s < 4; ++s) {
            const int wv = wvb + s * (PREP_VBLK * 4);         // head*32 + t
            const float* sp = vg + ((size_t)wv * TK + kg8 * 8) * D_DIM + dg * 8;
            float va[8][8];                        // [kv in group][d in group]
            #pragma unroll
            for (int i = 0; i < 8; ++i) {
                const float4* q4 = reinterpret_cast<const float4*>(sp + (size_t)i * D_DIM);
                float4 x = q4[0], y = q4[1];
                va[i][0] = x.x; va[i][1] = x.y; va[i][2] = x.z; va[i][3] = x.w;
                va[i][4] = y.x; va[i][5] = y.y; va[i][6] = y.z; va[i][7] = y.w;
            }
            unsigned short* db = vb + (size_t)wv * (TK * D_DIM);  // tile base
            #pragma unroll
            for (int j = 0; j < 8; ++j) {
                const int d = dg * 8 + j;          // d&7 == j
                uint4 w;
                w.x = pack_bf16(va[0][j], va[1][j]);
                w.y = pack_bf16(va[2][j], va[3][j]);
                w.z = pack_bf16(va[4][j], va[5][j]);
                w.w = pack_bf16(va[6][j], va[7][j]);
                *reinterpret_cast<uint4*>(db + d * D_DIM + 8 * (kg8 ^ j)) = w;
            }
        }
    }
}

// online-softmax for one 16-q group (relative domain, defer-max).
// SV: float[4][4]; MC/LI: running state; PL: this group's P base in LDS.
#define SOFTMAX_GROUP(SV, MC, LI, PL)                                          \
    {                                                                          \
        float x0 = fmax3(SV[0][0], SV[0][1], SV[0][2]);                        \
        float x1 = fmax3(SV[0][3], SV[1][0], SV[1][1]);                        \
        float x2 = fmax3(SV[1][2], SV[1][3], SV[2][0]);                        \
        float x3 = fmax3(SV[2][1], SV[2][2], SV[2][3]);                        \
        float x4 = fmax3(SV[3][0], SV[3][1], SV[3][2]);                        \
        float y0 = fmax3(x0, x1, x2);                                          \
        float y1 = fmax3(x3, x4, SV[3][3]);                                    \
        float rm = fmaxf(y0, y1);                                              \
        rm = fmaxf(rm, __shfl_xor(rm, 16, 64));                                \
        rm = fmaxf(rm, __shfl_xor(rm, 32, 64));                                \
        if (__any(rm > DEFER_THR)) {                                           \
            float mx    = fmaxf(rm, 0.f);                                      \
            float alpha = fast_exp2(-mx);                                      \
            LI *= alpha;                                                       \
            _Pragma("unroll")                                                  \
            for (int nc = 0; nc < 4; ++nc)                                     \
                _Pragma("unroll")                                              \
                for (int r = 0; r < 4; ++r) oacc##SV[nc][r] *= alpha;          \
            _Pragma("unroll")                                                  \
            for (int nt = 0; nt < 4; ++nt)                                     \
                _Pragma("unroll")                                              \
                for (int r = 0; r < 4; ++r) SV[nt][r] -= mx;                   \
            _Pragma("unroll")                                                  \
            for (int r = 0; r < 4; ++r) MC[r] -= mx;                           \
        }                                                                      \
        float rs = 0.f;                                                        \
        _Pragma("unroll")                                                      \
        for (int nt = 0; nt < 4; ++nt) {                                       \
            float e0 = fast_exp2(SV[nt][0]);                                   \
            float e1 = fast_exp2(SV[nt][1]);                                   \
            float e2 = fast_exp2(SV[nt][2]);                                   \
            float e3 = fast_exp2(SV[nt][3]);                                   \
            rs += (e0 + e1) + (e2 + e3);                                       \
            uint2 pw;                                                          \
            pw.x = pack_bf16_fast(e0, e1);                                     \
            pw.y = pack_bf16_fast(e2, e3);                                     \
            *reinterpret_cast<uint2*>(PL + ((nt * 32 + quad * 8) ^ swz)) = pw; \
        }                                                                      \
        rs += __shfl_xor(rs, 16, 64);                                          \
        rs += __shfl_xor(rs, 32, 64);                                          \
        LI += rs;                                                              \
    }

// ---------------------------------------------------------------------------
// Main: flash fwd, S^T formulation, bf16 K/V from workspace.
// Q-tile 128 (wave owns 32 q = 2 groups); K/V fragment reads feed 4 MFMAs.
// LDS = 2*8K (K) + 2*8K (V) + 16K (P) = 48K -> 2 blocks/CU (grid-limited).
// ---------------------------------------------------------------------------
__global__ __launch_bounds__(256, 2)
void fa_fwd(const float* __restrict__ qg,
            const unsigned short* __restrict__ kb,
            const unsigned short* __restrict__ vb,
            float* __restrict__ og)
{
    const int head = blockIdx.x;          // fast dim -> XCD spread
    const int pr   = blockIdx.y;          // 0..7: q-tile pairs {pr, 15-pr}
    const int tid  = threadIdx.x;
    const int wave = tid >> 6;
    const int lane = tid & 63;
    const int m16  = lane & 15;
    const int quad = lane >> 4;

    __shared__ unsigned short Kl[2][TK * D_DIM];     // swizzled [kv][d] bf16
    __shared__ unsigned short Vt[2][TK * D_DIM];     // swizzled [d][kv] bf16
    __shared__ unsigned short Pl[4][2][16 * TK];     // per-wave, per-group P

    const size_t hoff = (size_t)head * S_LEN * D_DIM;
    const unsigned short* kbh = kb + hoff;
    const unsigned short* vbh = vb + hoff;
    float* __restrict__ ogh = og + hoff;

    // swizzled byte columns within a 128B row (row&7 == m16&7 for all rows used)
    const int swz  = (m16 & 7) << 4;
    const int colA = (quad * 16) ^ swz;
    const int colB = (64 + quad * 16) ^ swz;
    const int rowB = m16 * 128;
    const int sgo  = wave * 512 + lane * 8;   // staging src offset (shorts)

    char* klds = (char*)&Kl[0][0];
    char* vlds = (char*)&Vt[0][0];
    char* plA  = (char*)&Pl[0][0][0] + wave * 4096 + m16 * 128;
    char* plB  = plA + 2048;
    char* kw   = klds + wave * 1024;          // wave-uniform stage dest (buf 0)
    char* vw   = vlds + wave * 1024;

    const float QSC = 0.18033688011112042f;   // 1/8 * log2(e): log2-domain scores

    for (int pass = 0; pass < 2; ++pass) {
        const int idx = (pass == 0) ? pr : (15 - pr);
        const int q0  = idx * 128;
        const int T   = (q0 >> 6) + 1;        // last kv-tile index (steps 0..T)

        // ---- Q fragments (B operand): group A rows q0+wave*16+m16,
        //      group B rows +64; k=d=quad*8+j; scaled 1/8*log2e
        bf16x8 qfA[2], qfB[2];
        {
            const float* qpA = qg + hoff + (size_t)(q0 + wave * 16 + m16) * D_DIM + quad * 8;
            #pragma unroll
            for (int c = 0; c < 2; ++c) {
                float4 a = reinterpret_cast<const float4*>(qpA + c * 32)[0];
                float4 b = reinterpret_cast<const float4*>(qpA + c * 32)[1];
                unsigned int u0 = pack_bf16(a.x * QSC, a.y * QSC);
                unsigned int u1 = pack_bf16(a.z * QSC, a.w * QSC);
                unsigned int u2 = pack_bf16(b.x * QSC, b.y * QSC);
                unsigned int u3 = pack_bf16(b.z * QSC, b.w * QSC);
                qfA[c][0] = (short)(u0 & 0xFFFF); qfA[c][1] = (short)(u0 >> 16);
                qfA[c][2] = (short)(u1 & 0xFFFF); qfA[c][3] = (short)(u1 >> 16);
                qfA[c][4] = (short)(u2 & 0xFFFF); qfA[c][5] = (short)(u2 >> 16);
                qfA[c][6] = (short)(u3 & 0xFFFF); qfA[c][7] = (short)(u3 >> 16);
            }
            const float* qpB = qpA + 64 * D_DIM;
            #pragma unroll
            for (int c = 0; c < 2; ++c) {
                float4 a = reinterpret_cast<const float4*>(qpB + c * 32)[0];
                float4 b = reinterpret_cast<const float4*>(qpB + c * 32)[1];
                unsigned int u0 = pack_bf16(a.x * QSC, a.y * QSC);
                unsigned int u1 = pack_bf16(a.z * QSC, a.w * QSC);
                unsigned int u2 = pack_bf16(b.x * QSC, b.y * QSC);
                unsigned int u3 = pack_bf16(b.z * QSC, b.w * QSC);
                qfB[c][0] = (short)(u0 & 0xFFFF); qfB[c][1] = (short)(u0 >> 16);
                qfB[c][2] = (short)(u1 & 0xFFFF); qfB[c][3] = (short)(u1 >> 16);
                qfB[c][4] = (short)(u2 & 0xFFFF); qfB[c][5] = (short)(u2 >> 16);
                qfB[c][6] = (short)(u3 & 0xFFFF); qfB[c][7] = (short)(u3 >> 16);
            }
        }

        float lA = 0.f, lB = 0.f;
        f32x4 mcA = (f32x4){MINIT, MINIT, MINIT, MINIT};
        f32x4 mcB = (f32x4){MINIT, MINIT, MINIT, MINIT};
        f32x4 oaccsvA[4], oaccsvB[4];   // names pair with SOFTMAX_GROUP macro
        #pragma unroll
        for (int nc = 0; nc < 4; ++nc) {
            oaccsvA[nc] = (f32x4){0.f, 0.f, 0.f, 0.f};
            oaccsvB[nc] = (f32x4){0.f, 0.f, 0.f, 0.f};
        }

        // ---- prologue: stage tile 0 into buf 0 (4x global_load_lds / wave)
        {
            const unsigned short* ks = kbh + sgo;
            const unsigned short* vs = vbh + sgo;
            stage16(ks,        kw);
            stage16(ks + 2048, kw + 4096);
            stage16(vs,        vw);
            stage16(vs + 2048, vw + 4096);
        }
        __syncthreads();   // compiler drains vmcnt(0) before s_barrier

        int cur = 0;
        for (int t = 0; t <= T; ++t) {
            // ---- issue next-tile stage first: latency hides under compute
            if (t < T) {
                const unsigned short* ks = kbh + (size_t)(t + 1) * 4096 + sgo;
                const unsigned short* vs = vbh + (size_t)(t + 1) * 4096 + sgo;
                const int nb = (cur ^ 1) * 8192;
                stage16(ks,        kw + nb);
                stage16(ks + 2048, kw + nb + 4096);
                stage16(vs,        vw + nb);
                stage16(vs + 2048, vw + nb + 4096);
            }

            const char* kt = klds + cur * 8192;
            const char* vt = vlds + cur * 8192;

            // ---- S^T = K·Q^T + (-m)  — each K fragment feeds both groups
            float svA[4][4], svB[4][4];
            __builtin_amdgcn_s_setprio(1);
            #pragma unroll
            for (int nt = 0; nt < 4; ++nt) {
                const char* kr = kt + nt * 2048 + rowB;
                bf16x8 kf0 = *reinterpret_cast<const bf16x8*>(kr + colA);
                bf16x8 kf1 = *reinterpret_cast<const bf16x8*>(kr + colB);
                f32x4 aA = __builtin_amdgcn_mfma_f32_16x16x32_bf16(kf0, qfA[0], mcA, 0, 0, 0);
                aA = __builtin_amdgcn_mfma_f32_16x16x32_bf16(kf1, qfA[1], aA, 0, 0, 0);
                f32x4 aB = __builtin_amdgcn_mfma_f32_16x16x32_bf16(kf0, qfB[0], mcB, 0, 0, 0);
                aB = __builtin_amdgcn_mfma_f32_16x16x32_bf16(kf1, qfB[1], aB, 0, 0, 0);
                #pragma unroll
                for (int r = 0; r < 4; ++r) { svA[nt][r] = aA[r]; svB[nt][r] = aB[r]; }
            }
            __builtin_amdgcn_s_setprio(0);

            // ---- causal masks. Group A diagonal at t==T-1, dead at t==T
            // (shift form covers both); group B diagonal at t==T.
            if (t >= T - 1) {
                const int sh = (t - (T - 1)) << 6;
                #pragma unroll
                for (int nt = 0; nt < 4; ++nt)
                    #pragma unroll
                    for (int r = 0; r < 4; ++r)
                        if (sh + nt * 16 + quad * 4 + r > wave * 16 + m16) svA[nt][r] = MASKV;
            }
            if (t == T) {
                #pragma unroll
                for (int nt = 0; nt < 4; ++nt)
                    #pragma unroll
                    for (int r = 0; r < 4; ++r)
                        if (nt * 16 + quad * 4 + r > wave * 16 + m16) svB[nt][r] = MASKV;
            }

            // ---- online softmax per group (relative domain, defer-max)
            SOFTMAX_GROUP(svA, mcA, lA, plA)
            SOFTMAX_GROUP(svB, mcB, lB, plB)

            // Pl is wave-private: intra-wave DS ordering only (keeps staging
            // loads in flight — no barrier here).
            asm volatile("s_waitcnt lgkmcnt(0)" ::: "memory");

            // ---- O^T += V^T·P^T — each V fragment feeds both groups
            bf16x8 pfA0 = *reinterpret_cast<const bf16x8*>(plA + colA);
            bf16x8 pfA1 = *reinterpret_cast<const bf16x8*>(plA + colB);
            bf16x8 pfB0 = *reinterpret_cast<const bf16x8*>(plB + colA);
            bf16x8 pfB1 = *reinterpret_cast<const bf16x8*>(plB + colB);
            __builtin_amdgcn_s_setprio(1);
            #pragma unroll
            for (int nc = 0; nc < 4; ++nc) {
                const char* vr = vt + nc * 2048 + rowB;
                bf16x8 vf0 = *reinterpret_cast<const bf16x8*>(vr + colA);
                bf16x8 vf1 = *reinterpret_cast<const bf16x8*>(vr + colB);
                oaccsvA[nc] = __builtin_amdgcn_mfma_f32_16x16x32_bf16(vf0, pfA0, oaccsvA[nc], 0, 0, 0);
                oaccsvA[nc] = __builtin_amdgcn_mfma_f32_16x16x32_bf16(vf1, pfA1, oaccsvA[nc], 0, 0, 0);
                oaccsvB[nc] = __builtin_amdgcn_mfma_f32_16x16x32_bf16(vf0, pfB0, oaccsvB[nc], 0, 0, 0);
                oaccsvB[nc] = __builtin_amdgcn_mfma_f32_16x16x32_bf16(vf1, pfB1, oaccsvB[nc], 0, 0, 0);
            }
            __builtin_amdgcn_s_setprio(0);

            __syncthreads();   // drains vmcnt (next tile staged) + lgkmcnt
            cur ^= 1;
        }

        // ---- epilogue: group A row q0+wave*16+m16, group B +64
        {
            float inv = 1.0f / lA;
            float* op = ogh + (size_t)(q0 + wave * 16 + m16) * D_DIM;
            #pragma unroll
            for (int nc = 0; nc < 4; ++nc) {
                float4 o4;
                o4.x = oaccsvA[nc][0] * inv;
                o4.y = oaccsvA[nc][1] * inv;
                o4.z = oaccsvA[nc][2] * inv;
                o4.w = oaccsvA[nc][3] * inv;
                reinterpret_cast<float4*>(op + nc * 16 + quad * 4)[0] = o4;
            }
        }
        {
            float inv = 1.0f / lB;
            float* op = ogh + (size_t)(q0 + 64 + wave * 16 + m16) * D_DIM;
            #pragma unroll
            for (int nc = 0; nc < 4; ++nc) {
                float4 o4;
                o4.x = oaccsvB[nc][0] * inv;
                o4.y = oaccsvB[nc][1] * inv;
                o4.z = oaccsvB[nc][2] * inv;
                o4.w = oaccsvB[nc][3] * inv;
                reinterpret_cast<float4*>(op + nc * 16 + quad * 4)[0] = o4;
            }
        }
    }
}

// ---------------------------------------------------------------------------
// Fallback (R6 kernel, verbatim) — used only if ws_size < 32 MiB.
// ---------------------------------------------------------------------------
__global__ __launch_bounds__(256, 4)
void fa_fwd_fb(const float* __restrict__ qg,
               const float* __restrict__ kg,
               const float* __restrict__ vg,
               float* __restrict__ og)
{
    const int head = blockIdx.x;
    const int pr   = blockIdx.y;
    const int tid  = threadIdx.x;
    const int wave = tid >> 6;
    const int lane = tid & 63;
    const int m16  = lane & 15;
    const int quad = lane >> 4;

    __shared__ unsigned short Kl[TK][LSTR];
    __shared__ unsigned short Vt[D_DIM][LSTR];
    __shared__ unsigned short Pl[4][16][LSTR];

    const size_t hoff = (size_t)head * S_LEN * D_DIM;
    const float* kh = kg + hoff;
    const float* vh = vg + hoff;

    const int ksr = tid >> 2;
    const int ksc = (tid & 3) << 4;
    const int va  = lane >> 3;
    const int vb  = lane & 7;
    const int vrr = wave * 16 + 2 * vb;
    const int vcc = 8 * va;
    const float LOG2E = 1.4426950408889634f;

    for (int pass = 0; pass < 2; ++pass) {
        const int q0 = ((pass == 0) ? pr : (31 - pr)) * TK;

        bf16x8 qf[2];
        {
            const float* qp = qg + hoff + (size_t)(q0 + wave * 16 + m16) * D_DIM + quad * 8;
            #pragma unroll
            for (int c = 0; c < 2; ++c) {
                float4 a = reinterpret_cast<const float4*>(qp + c * 32)[0];
                float4 b = reinterpret_cast<const float4*>(qp + c * 32)[1];
                unsigned int u0 = pack_bf16(a.x * 0.125f, a.y * 0.125f);
                unsigned int u1 = pack_bf16(a.z * 0.125f, a.w * 0.125f);
                unsigned int u2 = pack_bf16(b.x * 0.125f, b.y * 0.125f);
                unsigned int u3 = pack_bf16(b.z * 0.125f, b.w * 0.125f);
                qf[c][0] = (short)(u0 & 0xFFFF); qf[c][1] = (short)(u0 >> 16);
                qf[c][2] = (short)(u1 & 0xFFFF); qf[c][3] = (short)(u1 >> 16);
                qf[c][4] = (short)(u2 & 0xFFFF); qf[c][5] = (short)(u2 >> 16);
                qf[c][6] = (short)(u3 & 0xFFFF); qf[c][7] = (short)(u3 >> 16);
            }
        }

        float m_i = MNEG, l_i = 0.f;
        f32x4 oacc[4];
        #pragma unroll
        for (int nc = 0; nc < 4; ++nc) oacc[nc] = (f32x4){0.f, 0.f, 0.f, 0.f};

        float4 kA, kB, kC, kD, vA, vB, vC, vD;
        {
            const float* kp = kh + (size_t)ksr * D_DIM + ksc;
            kA = reinterpret_cast<const float4*>(kp)[0];
            kB = reinterpret_cast<const float4*>(kp)[1];
            kC = reinterpret_cast<const float4*>(kp)[2];
            kD = reinterpret_cast<const float4*>(kp)[3];
            const float* vp = vh + (size_t)vrr * D_DIM + vcc;
            vA = reinterpret_cast<const float4*>(vp)[0];
            vB = reinterpret_cast<const float4*>(vp)[1];
            vC = reinterpret_cast<const float4*>(vp + D_DIM)[0];
            vD = reinterpret_cast<const float4*>(vp + D_DIM)[1];
        }

        for (int j0 = 0; j0 <= q0; j0 += TK) {
            __syncthreads();
            {
                uint4 w0, w1;
                w0.x = pack_bf16(kA.x, kA.y); w0.y = pack_bf16(kA.z, kA.w);
                w0.z = pack_bf16(kB.x, kB.y); w0.w = pack_bf16(kB.z, kB.w);
                w1.x = pack_bf16(kC.x, kC.y); w1.y = pack_bf16(kC.z, kC.w);
                w1.z = pack_bf16(kD.x, kD.y); w1.w = pack_bf16(kD.z, kD.w);
                *reinterpret_cast<uint4*>(&Kl[ksr][ksc])     = w0;
                *reinterpret_cast<uint4*>(&Kl[ksr][ksc + 8]) = w1;

                float r0[8] = {vA.x, vA.y, vA.z, vA.w, vB.x, vB.y, vB.z, vB.w};
                float r1[8] = {vC.x, vC.y, vC.z, vC.w, vD.x, vD.y, vD.z, vD.w};
                #pragma unroll
                for (int jj = 0; jj < 8; ++jj) {
                    int j = (jj + va) & 7;
                    *reinterpret_cast<unsigned int*>(&Vt[vcc + j][vrr]) = pack_bf16(r0[j], r1[j]);
                }
            }
            __syncthreads();

            if (j0 + TK <= q0) {
                const float* kp = kh + (size_t)(j0 + TK + ksr) * D_DIM + ksc;
                kA = reinterpret_cast<const float4*>(kp)[0];
                kB = reinterpret_cast<const float4*>(kp)[1];
                kC = reinterpret_cast<const float4*>(kp)[2];
                kD = reinterpret_cast<const float4*>(kp)[3];
                const float* vp = vh + (size_t)(j0 + TK + vrr) * D_DIM + vcc;
                vA = reinterpret_cast<const float4*>(vp)[0];
                vB = reinterpret_cast<const float4*>(vp)[1];
                vC = reinterpret_cast<const float4*>(vp + D_DIM)[0];
                vD = reinterpret_cast<const float4*>(vp + D_DIM)[1];
            }

            float sv[4][4];
            #pragma unroll
            for (int nt = 0; nt < 4; ++nt) {
                f32x4 acc = (f32x4){0.f, 0.f, 0.f, 0.f};
                bf16x8 kf0 = *reinterpret_cast<const bf16x8*>(&Kl[nt * 16 + m16][quad * 8]);
                bf16x8 kf1 = *reinterpret_cast<const bf16x8*>(&Kl[nt * 16 + m16][32 + quad * 8]);
                acc = __builtin_amdgcn_mfma_f32_16x16x32_bf16(kf0, qf[0], acc, 0, 0, 0);
                acc = __builtin_amdgcn_mfma_f32_16x16x32_bf16(kf1, qf[1], acc, 0, 0, 0);
                #pragma unroll
                for (int r = 0; r < 4; ++r) sv[nt][r] = acc[r];
            }

            if (j0 == q0) {
                #pragma unroll
                for (int nt = 0; nt < 4; ++nt)
                    #pragma unroll
                    for (int r = 0; r < 4; ++r)
                        if (nt * 16 + quad * 4 + r > wave * 16 + m16) sv[nt][r] = MNEG;
            }

            float a0 = fmaxf(fmaxf(sv[0][0], sv[0][1]), fmaxf(sv[0][2], sv[0][3]));
            float a1 = fmaxf(fmaxf(sv[1][0], sv[1][1]), fmaxf(sv[1][2], sv[1][3]));
            float a2 = fmaxf(fmaxf(sv[2][0], sv[2][1]), fmaxf(sv[2][2], sv[2][3]));
            float a3 = fmaxf(fmaxf(sv[3][0], sv[3][1]), fmaxf(sv[3][2], sv[3][3]));
            float rm = fmaxf(fmaxf(a0, a1), fmaxf(a2, a3));
            rm = fmaxf(rm, __shfl_xor(rm, 16, 64));
            rm = fmaxf(rm, __shfl_xor(rm, 32, 64));
            float mnew  = fmaxf(m_i, rm);
            float alpha = fast_exp2((m_i - mnew) * LOG2E);
            float msc   = mnew * LOG2E;
            m_i = mnew;

            float rs = 0.f;
            #pragma unroll
            for (int nt = 0; nt < 4; ++nt) {
                float e0 = fast_exp2(fmaf(sv[nt][0], LOG2E, -msc));
                float e1 = fast_exp2(fmaf(sv[nt][1], LOG2E, -msc));
                float e2 = fast_exp2(fmaf(sv[nt][2], LOG2E, -msc));
                float e3 = fast_exp2(fmaf(sv[nt][3], LOG2E, -msc));
                rs += (e0 + e1) + (e2 + e3);
                uint2 pw;
                pw.x = pack_bf16(e0, e1);
                pw.y = pack_bf16(e2, e3);
                *reinterpret_cast<uint2*>(&Pl[wave][m16][nt * 16 + quad * 4]) = pw;
            }
            rs += __shfl_xor(rs, 16, 64);
            rs += __shfl_xor(rs, 32, 64);
            l_i = fmaf(alpha, l_i, rs);

            #pragma unroll
            for (int nc = 0; nc < 4; ++nc)
                #pragma unroll
                for (int r = 0; r < 4; ++r)
                    oacc[nc][r] *= alpha;

            asm volatile("s_waitcnt lgkmcnt(0)" ::: "memory");

            bf16x8 pf0 = *reinterpret_cast<const bf16x8*>(&Pl[wave][m16][quad * 8]);
            bf16x8 pf1 = *reinterpret_cast<const bf16x8*>(&Pl[wave][m16][32 + quad * 8]);
            #pragma unroll
            for (int nc = 0; nc < 4; ++nc) {
                bf16x8 vf0 = *reinterpret_cast<const bf16x8*>(&Vt[nc * 16 + m16][quad * 8]);
                bf16x8 vf1 = *reinterpret_cast<const bf16x8*>(&Vt[nc * 16 + m16][32 + quad * 8]);
                oacc[nc] = __builtin_amdgcn_mfma_f32_16x16x32_bf16(vf0, pf0, oacc[nc], 0, 0, 0);
                oacc[nc] = __builtin_amdgcn_mfma_f32_16x16x32_bf16(vf1, pf1, oacc[nc], 0, 0, 0);
            }
        }

        float inv = 1.0f / l_i;
        float* op = og + hoff + (size_t)(q0 + wave * 16 + m16) * D_DIM;
        #pragma unroll
        for (int nc = 0; nc < 4; ++nc) {
            float4 o4;
            o4.x = oacc[nc][0] * inv;
            o4.y = oacc[nc][1] * inv;
            o4.z = oacc[nc][2] * inv;
            o4.w = oacc[nc][3] * inv;
            reinterpret_cast<float4*>(op + nc * 16 + quad * 4)[0] = o4;
        }
    }
}

extern "C" void kernel_launch(void* const* d_in, const int* in_sizes, int n_in,
                              void* d_out, int out_size, void* d_ws, size_t ws_size,
                              hipStream_t stream) {
    const float* q = (const float*)d_in[0];
    const float* k = (const float*)d_in[1];
    const float* v = (const float*)d_in[2];
    float* o = (float*)d_out;
    const size_t kvShorts = (size_t)NHEAD * S_LEN * D_DIM;           // 8.39M
    const size_t wsNeed   = 2 * kvShorts * sizeof(unsigned short);   // 32 MiB
    if (d_ws != nullptr && ws_size >= wsNeed) {
        unsigned short* kb = (unsigned short*)d_ws;
        unsigned short* vb = kb + kvShorts;
        fa_prep<<<PREP_KBLK + PREP_VBLK, 256, 0, stream>>>(k, v, kb, vb);
        dim3 grid(NHEAD, 8);
        fa_fwd<<<grid, 256, 0, stream>>>(q, kb, vb, o);
    } else {
        dim3 grid(NHEAD, 16);
        fa_fwd_fb<<<grid, 256, 0, stream>>>(q, k, v, o);
    }
}

// Round 9
// 189.566 us; speedup vs baseline: 1.0751x; 1.0559x over previous
//
#include <hip/hip_runtime.h>
#include <math.h>

// B=4, H=16, S=2048, D=64 causal attention. fp32 in, fp32 out.
// R15 = R14 (32x32x16 MFMA, P in registers) with the permlane pair-reduce
// hardened. R14's inf diagnosis: plswapf passed two copies of the SAME value
// as "+v" asm operands -> register allocator may coalesce them into ONE VGPR
// -> v_permlane32_swap_b32 v,v (self-swap) -> both outputs = partner-half
// only -> at diagonal tiles the partner of a fully-masked lane gets
// rm=-30000, mx=fmax(rm,0)=0 -> exp2(~+1000)=inf. Fix: single asm block with
// earlyclobber "=&v" opaque copy (physically distinct registers guaranteed)
// + s_nop hazard guards before permlane reads of freshly-written VGPRs.
// plswap (pf assembly) operands are distinct values (not coalescible);
// s_nop guard added there too.
// All R14 structure unchanged: QK C-layout col(q)=lane&31 == PV B-operand
// col; row redistribution lane l<->l+32 via permlane32_swap (VALU). No P LDS,
// no DS shuffles. Grid 64x16 (idx=15-y), LDS 32KB, 3 blocks/CU.
// Carried: fa_prep, global_load_lds dbuf staging, T2 swizzle, log2-domain
// scores, relative defer-max (mc in MFMA C), v_perm pack, setprio.
// Fallback to R6 kernel if ws_size < 32 MiB.

#define S_LEN 2048
#define D_DIM 64
#define TK 64
#define NHEAD 64
#define MASKV -30000.0f   // causal mask value (always underflows exp2)
#define MINIT 1000.0f     // initial -m: sv(tile0) ~ +1000 -> forces rescale
#define DEFER_THR 12.0f   // log2 domain: P bounded by 2^12
#define MNEG -30000.0f    // fallback kernel only
#define LSTR 72           // fallback kernel only
#define PREP_KBLK 1024    // K-branch blocks (x4 chunks/thread)
#define PREP_VBLK 128     // V-branch blocks (x4 tiles/wave)

typedef __attribute__((ext_vector_type(8)))  short bf16x8;
typedef __attribute__((ext_vector_type(4)))  float f32x4;
typedef __attribute__((ext_vector_type(16))) float f32x16;

static __device__ __forceinline__ float fast_exp2(float x) {
#if __has_builtin(__builtin_amdgcn_exp2f)
    return __builtin_amdgcn_exp2f(x);   // v_exp_f32: 2^x, large-negative -> 0
#else
    float r;
    asm volatile("v_exp_f32 %0, %1\n\ts_nop 1" : "=v"(r) : "v"(x));
    return r;
#endif
}

// clang fuses nested fmaxf to v_max3_f32 (exact)
static __device__ __forceinline__ float fmax3(float a, float b, float c) {
    return fmaxf(fmaxf(a, b), c);
}

// round-half-up fp32->bf16 pair, packed into one dword (a=low, b=high)
static __device__ __forceinline__ unsigned int pack_bf16(float a, float b) {
    union { float f; unsigned int u; } ca, cb;
    ca.f = a; cb.f = b;
    unsigned int ua = ca.u + 0x8000u;
    unsigned int ub = cb.u + 0x8000u;
    return (ua >> 16) | (ub & 0xFFFF0000u);
}

// same bits as pack_bf16, 3 VALU ops: 2 adds + v_perm_b32 byte select.
static __device__ __forceinline__ unsigned int pack_bf16_fast(float a, float b) {
#if __has_builtin(__builtin_amdgcn_perm)
    union { float f; unsigned int u; } ca, cb;
    ca.f = a; cb.f = b;
    return __builtin_amdgcn_perm(cb.u + 0x8000u, ca.u + 0x8000u, 0x07060302u);
#else
    return pack_bf16(a, b);
#endif
}

// v_permlane32_swap_b32 vdst,vsrc: vdst.hi <-> vsrc.lo (LLVM-documented).
// After: x = [x_lo, y_lo], y = [x_hi, y_hi]. s_nop guards the VALU-write ->
// permlane-read hazard (compiler won't insert waits inside/around asm).
static __device__ __forceinline__ void plswap(unsigned int& x, unsigned int& y) {
    asm("s_nop 1\n\tv_permlane32_swap_b32 %0, %1" : "+v"(x), "+v"(y));
}
// Cross-half exchange of a float (lane l <-> l^32) on the VALU pipe.
// Single asm block; "=&v" earlyclobber FORCES b into a register distinct
// from a (R14 bug: two "+v" copies of the same value got coalesced into one
// VGPR -> self-swap -> own value lost -> mx=0 at masked-pairs -> inf).
// After: for every lane, {t,u} = {own x, partner x} (order lane-dependent);
// combining with a commutative op (fmax / add) is exact.
static __device__ __forceinline__ void plswapf(float x, float& t, float& u) {
    union { float f; unsigned int i; } c;
    c.f = x;
    unsigned int a = c.i, b;
    asm("v_mov_b32 %1, %0\n\t"
        "s_nop 1\n\t"
        "v_permlane32_swap_b32 %0, %1"
        : "+v"(a), "=&v"(b));
    c.i = a; t = c.f;
    c.i = b; u = c.f;
}

typedef const __attribute__((address_space(1))) unsigned int* gas1_t;
typedef __attribute__((address_space(3))) unsigned int* las3_t;
// async global->LDS, 16B per lane. LDS dest is wave-uniform base (+lane*16 in HW).
static __device__ __forceinline__ void stage16(const void* g, void* l) {
    __builtin_amdgcn_global_load_lds((gas1_t)g, (las3_t)l, 16, 0, 0);
}

// ---------------------------------------------------------------------------
// Prep (R13 v2): K -> kb (bf16, row-chunk-swizzled), V -> vb (bf16, transposed,
// tile-major, row-chunk-swizzled). Blocks [0,PREP_KBLK): K. Rest: V.
// ---------------------------------------------------------------------------
__global__ __launch_bounds__(256)
void fa_prep(const float* __restrict__ kg, const float* __restrict__ vg,
             unsigned short* __restrict__ kb, unsigned short* __restrict__ vb)
{
    const int tid = threadIdx.x;
    const int bid = blockIdx.x;
    if (bid < PREP_KBLK) {
        const int tcid = bid * 256 + tid;
        float4 a[4], b[4];
        int rowv[4], dstv[4];
        #pragma unroll
        for (int s = 0; s < 4; ++s) {
            const int cid = tcid + s * 262144;
            const int ch  = cid & 7;
            const int row = cid >> 3;
            const int kv  = row & (S_LEN - 1);
            const float4* sp = reinterpret_cast<const float4*>(kg + (size_t)row * D_DIM + ch * 8);
            a[s] = sp[0];
            b[s] = sp[1];
            rowv[s] = row;
            dstv[s] = ch ^ (kv & 7);               // T2 swizzle
        }
        #pragma unroll
        for (int s = 0; s < 4; ++s) {
            uint4 w;
            w.x = pack_bf16(a[s].x, a[s].y); w.y = pack_bf16(a[s].z, a[s].w);
            w.z = pack_bf16(b[s].x, b[s].y); w.w = pack_bf16(b[s].z, b[s].w);
            *reinterpret_cast<uint4*>(kb + (size_t)rowv[s] * D_DIM + dstv[s] * 8) = w;
        }
    } else {
        const int wvb  = (bid - PREP_KBLK) * 4 + (tid >> 6);
        const int lane = tid & 63;
        const int kg8  = lane >> 3;
        const int dg   = lane & 7;
        #pragma unroll 1
        for (int s = 0; s < 4; ++s) {
            const int wv = wvb + s * (PREP_VBLK * 4);         // head*32 + t
            const float* sp = vg + ((size_t)wv * TK + kg8 * 8) * D_DIM + dg * 8;
            float va[8][8];
            #pragma unroll
            for (int i = 0; i < 8; ++i) {
                const float4* q4 = reinterpret_cast<const float4*>(sp + (size_t)i * D_DIM);
                float4 x = q4[0], y = q4[1];
                va[i][0] = x.x; va[i][1] = x.y; va[i][2] = x.z; va[i][3] = x.w;
                va[i][4] = y.x; va[i][5] = y.y; va[i][6] = y.z; va[i][7] = y.w;
            }
            unsigned short* db = vb + (size_t)wv * (TK * D_DIM);
            #pragma unroll
            for (int j = 0; j < 8; ++j) {
                const int d = dg * 8 + j;          // d&7 == j
                uint4 w;
                w.x = pack_bf16(va[0][j], va[1][j]);
                w.y = pack_bf16(va[2][j], va[3][j]);
                w.z = pack_bf16(va[4][j], va[5][j]);
                w.w = pack_bf16(va[6][j], va[7][j]);
                *reinterpret_cast<uint4*>(db + d * D_DIM + 8 * (kg8 ^ j)) = w;
            }
        }
    }
}

// ---------------------------------------------------------------------------
// Main: flash fwd, S^T formulation, 32x32x16 MFMA, P in registers.
// One 128-q tile per block (idx = 15 - blockIdx.y); wave owns 32 q.
// LDS = 2*8K (K dbuf) + 2*8K (V dbuf) = 32 KB -> 3 blocks/CU at 3 waves/EU.
// ---------------------------------------------------------------------------
__global__ __launch_bounds__(256, 3)
void fa_fwd(const float* __restrict__ qg,
            const unsigned short* __restrict__ kb,
            const unsigned short* __restrict__ vb,
            float* __restrict__ og)
{
    const int head = blockIdx.x;           // fast dim -> XCD spread
    const int idx  = 15 - (int)blockIdx.y; // big tiles dispatch first
    const int q0   = idx * 128;
    const int tid  = threadIdx.x;
    const int wave = tid >> 6;
    const int lane = tid & 63;
    const int r0   = lane & 31;            // row/col-in-32 index
    const int h    = lane >> 5;            // half: lane<32 / lane>=32
    const int sw   = r0 & 7;               // T2 swizzle key (rows r0 and r0+32 share it)

    __shared__ unsigned short Kl[2][TK * D_DIM];   // swizzled [kv][d] bf16
    __shared__ unsigned short Vt[2][TK * D_DIM];   // swizzled [d][kv] bf16

    const size_t hoff = (size_t)head * S_LEN * D_DIM;
    const unsigned short* kbh = kb + hoff;
    const unsigned short* vbh = vb + hoff;
    float* __restrict__ ogh = og + hoff;

    const int sgo  = wave * 512 + lane * 8;    // staging src offset (shorts)
    char* klds = (char*)&Kl[0][0];
    char* vlds = (char*)&Vt[0][0];
    char* kw   = klds + wave * 1024;           // wave-uniform stage dest (buf 0)
    char* vw   = vlds + wave * 1024;

    const int koff = r0 * 128;                 // row base (bytes)
    int coff[4];                               // swizzled 16B chunk offset per k-slice
    #pragma unroll
    for (int s = 0; s < 4; ++s) coff[s] = ((2 * s + h) ^ sw) << 4;

    const int T  = 2 * idx + 1;                // last kv-tile
    const int td = 2 * idx + (wave >> 1);      // this wave's diagonal tile

    const float QSC = 0.18033688011112042f;    // 1/8 * log2(e)

    // ---- Q fragments (B operand): col n=q=lane&31 (+32*wave), k=8h+j per 16-slice
    bf16x8 qf[4];
    {
        const int q = q0 + 32 * wave + r0;
        const float* qp = qg + hoff + (size_t)q * D_DIM;
        #pragma unroll
        for (int s = 0; s < 4; ++s) {
            const float* p = qp + 16 * s + 8 * h;
            float4 a = reinterpret_cast<const float4*>(p)[0];
            float4 b = reinterpret_cast<const float4*>(p)[1];
            unsigned int u0 = pack_bf16(a.x * QSC, a.y * QSC);
            unsigned int u1 = pack_bf16(a.z * QSC, a.w * QSC);
            unsigned int u2 = pack_bf16(b.x * QSC, b.y * QSC);
            unsigned int u3 = pack_bf16(b.z * QSC, b.w * QSC);
            qf[s][0] = (short)(u0 & 0xFFFF); qf[s][1] = (short)(u0 >> 16);
            qf[s][2] = (short)(u1 & 0xFFFF); qf[s][3] = (short)(u1 >> 16);
            qf[s][4] = (short)(u2 & 0xFFFF); qf[s][5] = (short)(u2 >> 16);
            qf[s][6] = (short)(u3 & 0xFFFF); qf[s][7] = (short)(u3 >> 16);
        }
    }

    float l_i = 0.f;
    f32x16 mc, oacc0, oacc1;
    #pragma unroll
    for (int g = 0; g < 16; ++g) { mc[g] = MINIT; oacc0[g] = 0.f; oacc1[g] = 0.f; }

    // ---- prologue: stage tile 0 into buf 0
    {
        const unsigned short* ks = kbh + sgo;
        const unsigned short* vs = vbh + sgo;
        stage16(ks,        kw);
        stage16(ks + 2048, kw + 4096);
        stage16(vs,        vw);
        stage16(vs + 2048, vw + 4096);
    }
    __syncthreads();

    int cur = 0;
    for (int t = 0; t <= T; ++t) {
        if (t < T) {
            const unsigned short* ks = kbh + (size_t)(t + 1) * 4096 + sgo;
            const unsigned short* vs = vbh + (size_t)(t + 1) * 4096 + sgo;
            const int nb = (cur ^ 1) * 8192;
            stage16(ks,        kw + nb);
            stage16(ks + 2048, kw + nb + 4096);
            stage16(vs,        vw + nb);
            stage16(vs + 2048, vw + nb + 4096);
        }

        if (t <= td) {   // wave-uniform; dead waves skip compute, still barrier
            const char* kt = klds + cur * 8192;
            const char* vt = vlds + cur * 8192;

            // ---- S^T = K·Q^T + (-m): s0 = kv rows 0..31, s1 = 32..63 of tile
            f32x16 s0, s1;
            __builtin_amdgcn_s_setprio(1);
            {
                bf16x8 k0 = *reinterpret_cast<const bf16x8*>(kt + koff + coff[0]);
                bf16x8 k1 = *reinterpret_cast<const bf16x8*>(kt + koff + 4096 + coff[0]);
                s0 = __builtin_amdgcn_mfma_f32_32x32x16_bf16(k0, qf[0], mc, 0, 0, 0);
                s1 = __builtin_amdgcn_mfma_f32_32x32x16_bf16(k1, qf[0], mc, 0, 0, 0);
            }
            #pragma unroll
            for (int s = 1; s < 4; ++s) {
                bf16x8 k0 = *reinterpret_cast<const bf16x8*>(kt + koff + coff[s]);
                bf16x8 k1 = *reinterpret_cast<const bf16x8*>(kt + koff + 4096 + coff[s]);
                s0 = __builtin_amdgcn_mfma_f32_32x32x16_bf16(k0, qf[s], s0, 0, 0, 0);
                s1 = __builtin_amdgcn_mfma_f32_32x32x16_bf16(k1, qf[s], s1, 0, 0, 0);
            }
            __builtin_amdgcn_s_setprio(0);

            // ---- causal mask at this wave's diagonal tile.
            // row(reg) = (reg&3)+8*(reg>>2)+4h (+32 for s1); col = r0.
            if (t == td) {
                if ((wave & 1) == 0) {
                    #pragma unroll
                    for (int g = 0; g < 16; ++g) {
                        const int rl = (g & 3) + 8 * (g >> 2) + 4 * h;
                        if (rl > r0) s0[g] = MASKV;
                        s1[g] = MASKV;                   // rows 32..63 all > col
                    }
                } else {
                    #pragma unroll
                    for (int g = 0; g < 16; ++g) {
                        const int rl = (g & 3) + 8 * (g >> 2) + 4 * h;
                        if (rl > r0) s1[g] = MASKV;      // s0 rows never masked
                    }
                }
            }

            // ---- softmax (relative domain, defer-max); column pair via permlane
            float t0 = fmax3(s0[0],  s0[1],  s0[2]);
            float t1 = fmax3(s0[3],  s0[4],  s0[5]);
            float t2 = fmax3(s0[6],  s0[7],  s0[8]);
            float t3 = fmax3(s0[9],  s0[10], s0[11]);
            float t4 = fmax3(s0[12], s0[13], s0[14]);
            float t5 = fmax3(s0[15], s1[0],  s1[1]);
            float t6 = fmax3(s1[2],  s1[3],  s1[4]);
            float t7 = fmax3(s1[5],  s1[6],  s1[7]);
            float t8 = fmax3(s1[8],  s1[9],  s1[10]);
            float t9 = fmax3(s1[11], s1[12], s1[13]);
            float u0 = fmax3(t0, t1, t2);
            float u1 = fmax3(t3, t4, t5);
            float u2 = fmax3(t6, t7, t8);
            float u3 = fmax3(t9, s1[14], s1[15]);
            float rm = fmaxf(fmax3(u0, u1, u2), u3);
            { float a, b; plswapf(rm, a, b); rm = fmaxf(a, b); }

            if (__any(rm > DEFER_THR)) {
                float mx    = fmaxf(rm, 0.f);
                float alpha = fast_exp2(-mx);
                l_i *= alpha;
                #pragma unroll
                for (int g = 0; g < 16; ++g) {
                    oacc0[g] *= alpha; oacc1[g] *= alpha;
                    s0[g] -= mx; s1[g] -= mx;
                    mc[g] -= mx;
                }
            }

            float ea[16], eb[16];
            float rs = 0.f;
            #pragma unroll
            for (int g = 0; g < 16; ++g) {
                ea[g] = fast_exp2(s0[g]);
                eb[g] = fast_exp2(s1[g]);
            }
            #pragma unroll
            for (int g = 0; g < 16; ++g) rs += ea[g] + eb[g];
            { float a, b; plswapf(rs, a, b); l_i += a + b; }

            // ---- P -> B-fragments in-register: pack pairs, permlane32-swap.
            // Semantics vdst.hi<->vsrc.lo: after plswap(x,y) x=[x_lo,y_lo],
            // y=[x_hi,y_hi]; (pa[0],pa[2]) and (pa[1],pa[3]) swaps assemble
            // each 16-kv slice's bf16x8 fragment in place.
            unsigned int pa[8], pb[8];
            #pragma unroll
            for (int k = 0; k < 8; ++k) {
                pa[k] = pack_bf16_fast(ea[2 * k], ea[2 * k + 1]);
                pb[k] = pack_bf16_fast(eb[2 * k], eb[2 * k + 1]);
            }
            plswap(pa[0], pa[2]); plswap(pa[1], pa[3]);
            plswap(pa[4], pa[6]); plswap(pa[5], pa[7]);
            plswap(pb[0], pb[2]); plswap(pb[1], pb[3]);
            plswap(pb[4], pb[6]); plswap(pb[5], pb[7]);
            union { unsigned int u[4]; bf16x8 v; } pf[4];
            pf[0].u[0] = pa[0]; pf[0].u[1] = pa[1]; pf[0].u[2] = pa[2]; pf[0].u[3] = pa[3];
            pf[1].u[0] = pa[4]; pf[1].u[1] = pa[5]; pf[1].u[2] = pa[6]; pf[1].u[3] = pa[7];
            pf[2].u[0] = pb[0]; pf[2].u[1] = pb[1]; pf[2].u[2] = pb[2]; pf[2].u[3] = pb[3];
            pf[3].u[0] = pb[4]; pf[3].u[1] = pb[5]; pf[3].u[2] = pb[6]; pf[3].u[3] = pb[7];

            // ---- O^T += V^T·P^T  (A = V^T frags from LDS, B = pf in regs)
            __builtin_amdgcn_s_setprio(1);
            #pragma unroll
            for (int s = 0; s < 4; ++s) {
                bf16x8 v0 = *reinterpret_cast<const bf16x8*>(vt + koff + coff[s]);
                bf16x8 v1 = *reinterpret_cast<const bf16x8*>(vt + koff + 4096 + coff[s]);
                oacc0 = __builtin_amdgcn_mfma_f32_32x32x16_bf16(v0, pf[s].v, oacc0, 0, 0, 0);
                oacc1 = __builtin_amdgcn_mfma_f32_32x32x16_bf16(v1, pf[s].v, oacc1, 0, 0, 0);
            }
            __builtin_amdgcn_s_setprio(0);
        }

        __syncthreads();   // drains vmcnt (next tile staged) + lgkmcnt
        cur ^= 1;
    }

    // ---- epilogue: lane owns col q = q0+32*wave+r0; rows d from C layout
    {
        const float inv = 1.0f / l_i;
        float* op = ogh + (size_t)(q0 + 32 * wave + r0) * D_DIM;
        #pragma unroll
        for (int a = 0; a < 4; ++a) {
            float4 o4;
            o4.x = oacc0[4 * a + 0] * inv;
            o4.y = oacc0[4 * a + 1] * inv;
            o4.z = oacc0[4 * a + 2] * inv;
            o4.w = oacc0[4 * a + 3] * inv;
            reinterpret_cast<float4*>(op + 8 * a + 4 * h)[0] = o4;
        }
        #pragma unroll
        for (int a = 0; a < 4; ++a) {
            float4 o4;
            o4.x = oacc1[4 * a + 0] * inv;
            o4.y = oacc1[4 * a + 1] * inv;
            o4.z = oacc1[4 * a + 2] * inv;
            o4.w = oacc1[4 * a + 3] * inv;
            reinterpret_cast<float4*>(op + 32 + 8 * a + 4 * h)[0] = o4;
        }
    }
}

// ---------------------------------------------------------------------------
// Fallback (R6 kernel, verbatim) — used only if ws_size < 32 MiB.
// ---------------------------------------------------------------------------
__global__ __launch_bounds__(256, 4)
void fa_fwd_fb(const float* __restrict__ qg,
               const float* __restrict__ kg,
               const float* __restrict__ vg,
               float* __restrict__ og)
{
    const int head = blockIdx.x;
    const int pr   = blockIdx.y;
    const int tid  = threadIdx.x;
    const int wave = tid >> 6;
    const int lane = tid & 63;
    const int m16  = lane & 15;
    const int quad = lane >> 4;

    __shared__ unsigned short Kl[TK][LSTR];
    __shared__ unsigned short Vt[D_DIM][LSTR];
    __shared__ unsigned short Pl[4][16][LSTR];

    const size_t hoff = (size_t)head * S_LEN * D_DIM;
    const float* kh = kg + hoff;
    const float* vh = vg + hoff;

    const int ksr = tid >> 2;
    const int ksc = (tid & 3) << 4;
    const int va  = lane >> 3;
    const int vb  = lane & 7;
    const int vrr = wave * 16 + 2 * vb;
    const int vcc = 8 * va;
    const float LOG2E = 1.4426950408889634f;

    for (int pass = 0; pass < 2; ++pass) {
        const int q0 = ((pass == 0) ? pr : (31 - pr)) * TK;

        bf16x8 qf[2];
        {
            const float* qp = qg + hoff + (size_t)(q0 + wave * 16 + m16) * D_DIM + quad * 8;
            #pragma unroll
            for (int c = 0; c < 2; ++c) {
                float4 a = reinterpret_cast<const float4*>(qp + c * 32)[0];
                float4 b = reinterpret_cast<const float4*>(qp + c * 32)[1];
                unsigned int u0 = pack_bf16(a.x * 0.125f, a.y * 0.125f);
                unsigned int u1 = pack_bf16(a.z * 0.125f, a.w * 0.125f);
                unsigned int u2 = pack_bf16(b.x * 0.125f, b.y * 0.125f);
                unsigned int u3 = pack_bf16(b.z * 0.125f, b.w * 0.125f);
                qf[c][0] = (short)(u0 & 0xFFFF); qf[c][1] = (short)(u0 >> 16);
                qf[c][2] = (short)(u1 & 0xFFFF); qf[c][3] = (short)(u1 >> 16);
                qf[c][4] = (short)(u2 & 0xFFFF); qf[c][5] = (short)(u2 >> 16);
                qf[c][6] = (short)(u3 & 0xFFFF); qf[c][7] = (short)(u3 >> 16);
            }
        }

        float m_i = MNEG, l_i = 0.f;
        f32x4 oacc[4];
        #pragma unroll
        for (int nc = 0; nc < 4; ++nc) oacc[nc] = (f32x4){0.f, 0.f, 0.f, 0.f};

        float4 kA, kB, kC, kD, vA, vB, vC, vD;
        {
            const float* kp = kh + (size_t)ksr * D_DIM + ksc;
            kA = reinterpret_cast<const float4*>(kp)[0];
            kB = reinterpret_cast<const float4*>(kp)[1];
            kC = reinterpret_cast<const float4*>(kp)[2];
            kD = reinterpret_cast<const float4*>(kp)[3];
            const float* vp = vh + (size_t)vrr * D_DIM + vcc;
            vA = reinterpret_cast<const float4*>(vp)[0];
            vB = reinterpret_cast<const float4*>(vp)[1];
            vC = reinterpret_cast<const float4*>(vp + D_DIM)[0];
            vD = reinterpret_cast<const float4*>(vp + D_DIM)[1];
        }

        for (int j0 = 0; j0 <= q0; j0 += TK) {
            __syncthreads();
            {
                uint4 w0, w1;
                w0.x = pack_bf16(kA.x, kA.y); w0.y = pack_bf16(kA.z, kA.w);
                w0.z = pack_bf16(kB.x, kB.y); w0.w = pack_bf16(kB.z, kB.w);
                w1.x = pack_bf16(kC.x, kC.y); w1.y = pack_bf16(kC.z, kC.w);
                w1.z = pack_bf16(kD.x, kD.y); w1.w = pack_bf16(kD.z, kD.w);
                *reinterpret_cast<uint4*>(&Kl[ksr][ksc])     = w0;
                *reinterpret_cast<uint4*>(&Kl[ksr][ksc + 8]) = w1;

                float r0[8] = {vA.x, vA.y, vA.z, vA.w, vB.x, vB.y, vB.z, vB.w};
                float r1[8] = {vC.x, vC.y, vC.z, vC.w, vD.x, vD.y, vD.z, vD.w};
                #pragma unroll
                for (int jj = 0; jj < 8; ++jj) {
                    int j = (jj + va) & 7;
                    *reinterpret_cast<unsigned int*>(&Vt[vcc + j][vrr]) = pack_bf16(r0[j], r1[j]);
                }
            }
            __syncthreads();

            if (j0 + TK <= q0) {
                const float* kp = kh + (size_t)(j0 + TK + ksr) * D_DIM + ksc;
                kA = reinterpret_cast<const float4*>(kp)[0];
                kB = reinterpret_cast<const float4*>(kp)[1];
                kC = reinterpret_cast<const float4*>(kp)[2];
                kD = reinterpret_cast<const float4*>(kp)[3];
                const float* vp = vh + (size_t)(j0 + TK + vrr) * D_DIM + vcc;
                vA = reinterpret_cast<const float4*>(vp)[0];
                vB = reinterpret_cast<const float4*>(vp)[1];
                vC = reinterpret_cast<const float4*>(vp + D_DIM)[0];
                vD = reinterpret_cast<const float4*>(vp + D_DIM)[1];
            }

            float sv[4][4];
            #pragma unroll
            for (int nt = 0; nt < 4; ++nt) {
                f32x4 acc = (f32x4){0.f, 0.f, 0.f, 0.f};
                bf16x8 kf0 = *reinterpret_cast<const bf16x8*>(&Kl[nt * 16 + m16][quad * 8]);
                bf16x8 kf1 = *reinterpret_cast<const bf16x8*>(&Kl[nt * 16 + m16][32 + quad * 8]);
                acc = __builtin_amdgcn_mfma_f32_16x16x32_bf16(kf0, qf[0], acc, 0, 0, 0);
                acc = __builtin_amdgcn_mfma_f32_16x16x32_bf16(kf1, qf[1], acc, 0, 0, 0);
                #pragma unroll
                for (int r = 0; r < 4; ++r) sv[nt][r] = acc[r];
            }

            if (j0 == q0) {
                #pragma unroll
                for (int nt = 0; nt < 4; ++nt)
                    #pragma unroll
                    for (int r = 0; r < 4; ++r)
                        if (nt * 16 + quad * 4 + r > wave * 16 + m16) sv[nt][r] = MNEG;
            }

            float a0 = fmaxf(fmaxf(sv[0][0], sv[0][1]), fmaxf(sv[0][2], sv[0][3]));
            float a1 = fmaxf(fmaxf(sv[1][0], sv[1][1]), fmaxf(sv[1][2], sv[1][3]));
            float a2 = fmaxf(fmaxf(sv[2][0], sv[2][1]), fmaxf(sv[2][2], sv[2][3]));
            float a3 = fmaxf(fmaxf(sv[3][0], sv[3][1]), fmaxf(sv[3][2], sv[3][3]));
            float rm = fmaxf(fmaxf(a0, a1), fmaxf(a2, a3));
            rm = fmaxf(rm, __shfl_xor(rm, 16, 64));
            rm = fmaxf(rm, __shfl_xor(rm, 32, 64));
            float mnew  = fmaxf(m_i, rm);
            float alpha = fast_exp2((m_i - mnew) * LOG2E);
            float msc   = mnew * LOG2E;
            m_i = mnew;

            float rs = 0.f;
            #pragma unroll
            for (int nt = 0; nt < 4; ++nt) {
                float e0 = fast_exp2(fmaf(sv[nt][0], LOG2E, -msc));
                float e1 = fast_exp2(fmaf(sv[nt][1], LOG2E, -msc));
                float e2 = fast_exp2(fmaf(sv[nt][2], LOG2E, -msc));
                float e3 = fast_exp2(fmaf(sv[nt][3], LOG2E, -msc));
                rs += (e0 + e1) + (e2 + e3);
                uint2 pw;
                pw.x = pack_bf16(e0, e1);
                pw.y = pack_bf16(e2, e3);
                *reinterpret_cast<uint2*>(&Pl[wave][m16][nt * 16 + quad * 4]) = pw;
            }
            rs += __shfl_xor(rs, 16, 64);
            rs += __shfl_xor(rs, 32, 64);
            l_i = fmaf(alpha, l_i, rs);

            #pragma unroll
            for (int nc = 0; nc < 4; ++nc)
                #pragma unroll
                for (int r = 0; r < 4; ++r)
                    oacc[nc][r] *= alpha;

            asm volatile("s_waitcnt lgkmcnt(0)" ::: "memory");

            bf16x8 pf0 = *reinterpret_cast<const bf16x8*>(&Pl[wave][m16][quad * 8]);
            bf16x8 pf1 = *reinterpret_cast<const bf16x8*>(&Pl[wave][m16][32 + quad * 8]);
            #pragma unroll
            for (int nc = 0; nc < 4; ++nc) {
                bf16x8 vf0 = *reinterpret_cast<const bf16x8*>(&Vt[nc * 16 + m16][quad * 8]);
                bf16x8 vf1 = *reinterpret_cast<const bf16x8*>(&Vt[nc * 16 + m16][32 + quad * 8]);
                oacc[nc] = __builtin_amdgcn_mfma_f32_16x16x32_bf16(vf0, pf0, oacc[nc], 0, 0, 0);
                oacc[nc] = __builtin_amdgcn_mfma_f32_16x16x32_bf16(vf1, pf1, oacc[nc], 0, 0, 0);
            }
        }

        float inv = 1.0f / l_i;
        float* op = og + hoff + (size_t)(q0 + wave * 16 + m16) * D_DIM;
        #pragma unroll
        for (int nc = 0; nc < 4; ++nc) {
            float4 o4;
            o4.x = oacc[nc][0] * inv;
            o4.y = oacc[nc][1] * inv;
            o4.z = oacc[nc][2] * inv;
            o4.w = oacc[nc][3] * inv;
            reinterpret_cast<float4*>(op + nc * 16 + quad * 4)[0] = o4;
        }
    }
}

extern "C" void kernel_launch(void* const* d_in, const int* in_sizes, int n_in,
                              void* d_out, int out_size, void* d_ws, size_t ws_size,
                              hipStream_t stream) {
    const float* q = (const float*)d_in[0];
    const float* k = (const float*)d_in[1];
    const float* v = (const float*)d_in[2];
    float* o = (float*)d_out;
    const size_t kvShorts = (size_t)NHEAD * S_LEN * D_DIM;           // 8.39M
    const size_t wsNeed   = 2 * kvShorts * sizeof(unsigned short);   // 32 MiB
    if (d_ws != nullptr && ws_size >= wsNeed) {
        unsigned short* kbp = (unsigned short*)d_ws;
        unsigned short* vbp = kbp + kvShorts;
        fa_prep<<<PREP_KBLK + PREP_VBLK, 256, 0, stream>>>(k, v, kbp, vbp);
        dim3 grid(NHEAD, 16);
        fa_fwd<<<grid, 256, 0, stream>>>(q, kbp, vbp, o);
    } else {
        dim3 grid(NHEAD, 16);
        fa_fwd_fb<<<grid, 256, 0, stream>>>(q, k, v, o);
    }
}

// Round 10
// 188.152 us; speedup vs baseline: 1.0831x; 1.0075x over previous
//
#include <hip/hip_runtime.h>
#include <math.h>

// B=4, H=16, S=2048, D=64 causal attention. fp32 in, fp32 out.
// R16 = R15 (32x32x16 MFMA, P in registers) + two exact changes:
//  1. Fragment-major K/V workspace/LDS layout: tile = [half][kchunk][row][16B]
//     (8KB). A-fragment ds_read becomes base + (2s+h)*512 + r0*16 -> each
//     32-lane half reads ONE CONTIGUOUS 512B block: ZERO bank conflicts
//     (R15: structural 4-way, 4.33e6 conflict cycles = 10% of wall, since
//     32 rows x same 16B chunk column can only spread over 8 chunk slots).
//     No swizzle at all; offsets fold to compile-time immediates.
//  2. __launch_bounds__(256,4): 4 blocks/CU resident (was 3) -> occupancy
//     33% -> ~50%; LDS 4x32KB=128KB fits, VGPR 64 not binding.
// Carried from R15: QK C-layout col(q)=lane&31 == PV B-operand col; lane
// l<->l+32 row redistribution via hardened v_permlane32_swap (earlyclobber
// copy + s_nop guards — R14's inf was operand coalescing into a self-swap);
// no P LDS, no DS shuffles; relative defer-max (mc in MFMA C); log2-domain
// scores; v_perm pack; setprio; fa_prep O(S) conversion; dbuf staging.
// Fallback to R6 kernel if ws_size < 32 MiB.

#define S_LEN 2048
#define D_DIM 64
#define TK 64
#define NHEAD 64
#define MASKV -30000.0f   // causal mask value (always underflows exp2)
#define MINIT 1000.0f     // initial -m: sv(tile0) ~ +1000 -> forces rescale
#define DEFER_THR 12.0f   // log2 domain: P bounded by 2^12
#define MNEG -30000.0f    // fallback kernel only
#define LSTR 72           // fallback kernel only
#define PREP_KBLK 1024    // K-branch blocks (x4 chunks/thread)
#define PREP_VBLK 128     // V-branch blocks (x4 tiles/wave)

typedef __attribute__((ext_vector_type(8)))  short bf16x8;
typedef __attribute__((ext_vector_type(4)))  float f32x4;
typedef __attribute__((ext_vector_type(16))) float f32x16;

static __device__ __forceinline__ float fast_exp2(float x) {
#if __has_builtin(__builtin_amdgcn_exp2f)
    return __builtin_amdgcn_exp2f(x);   // v_exp_f32: 2^x, large-negative -> 0
#else
    float r;
    asm volatile("v_exp_f32 %0, %1\n\ts_nop 1" : "=v"(r) : "v"(x));
    return r;
#endif
}

// clang fuses nested fmaxf to v_max3_f32 (exact)
static __device__ __forceinline__ float fmax3(float a, float b, float c) {
    return fmaxf(fmaxf(a, b), c);
}

// round-half-up fp32->bf16 pair, packed into one dword (a=low, b=high)
static __device__ __forceinline__ unsigned int pack_bf16(float a, float b) {
    union { float f; unsigned int u; } ca, cb;
    ca.f = a; cb.f = b;
    unsigned int ua = ca.u + 0x8000u;
    unsigned int ub = cb.u + 0x8000u;
    return (ua >> 16) | (ub & 0xFFFF0000u);
}

// same bits as pack_bf16, 3 VALU ops: 2 adds + v_perm_b32 byte select.
static __device__ __forceinline__ unsigned int pack_bf16_fast(float a, float b) {
#if __has_builtin(__builtin_amdgcn_perm)
    union { float f; unsigned int u; } ca, cb;
    ca.f = a; cb.f = b;
    return __builtin_amdgcn_perm(cb.u + 0x8000u, ca.u + 0x8000u, 0x07060302u);
#else
    return pack_bf16(a, b);
#endif
}

// v_permlane32_swap_b32 vdst,vsrc: vdst.hi <-> vsrc.lo (LLVM-documented).
// After: x = [x_lo, y_lo], y = [x_hi, y_hi]. s_nop guards the VALU-write ->
// permlane-read hazard (compiler won't insert waits inside/around asm).
static __device__ __forceinline__ void plswap(unsigned int& x, unsigned int& y) {
    asm("s_nop 1\n\tv_permlane32_swap_b32 %0, %1" : "+v"(x), "+v"(y));
}
// Cross-half exchange of a float (lane l <-> l^32) on the VALU pipe.
// Single asm block; "=&v" earlyclobber FORCES b into a register distinct
// from a (R14 bug: two "+v" copies of the same value got coalesced into one
// VGPR -> self-swap -> own value lost -> mx=0 at masked-pairs -> inf).
// After: {t,u} = {own x, partner x} (order lane-dependent); combining with a
// commutative op (fmax / add) is exact.
static __device__ __forceinline__ void plswapf(float x, float& t, float& u) {
    union { float f; unsigned int i; } c;
    c.f = x;
    unsigned int a = c.i, b;
    asm("v_mov_b32 %1, %0\n\t"
        "s_nop 1\n\t"
        "v_permlane32_swap_b32 %0, %1"
        : "+v"(a), "=&v"(b));
    c.i = a; t = c.f;
    c.i = b; u = c.f;
}

typedef const __attribute__((address_space(1))) unsigned int* gas1_t;
typedef __attribute__((address_space(3))) unsigned int* las3_t;
// async global->LDS, 16B per lane. LDS dest is wave-uniform base (+lane*16 in HW).
static __device__ __forceinline__ void stage16(const void* g, void* l) {
    __builtin_amdgcn_global_load_lds((gas1_t)g, (las3_t)l, 16, 0, 0);
}

// ---------------------------------------------------------------------------
// Prep v3: fragment-major tile layout (shorts within an 8KB = 4096-short tile):
//   K tile (kv 0..63, d 0..63):  off = (kv>>5)*2048 + (d>>3)*256 + (kv&31)*8 + (d&7)... 
//     stored PER 16B CHUNK: chunk (d-chunk ch) holds d=8ch..8ch+7 for one kv:
//     off = (kv>>5)*2048 + ch*256 + (kv&31)*8   [16B = 8 shorts, d ascending]
//   V tile (transposed; row = d, k = kv): off = (d>>5)*2048 + (kv>>3)*256 +
//     (d&31)*8 + (kv&7)
// fa_fwd reads lane L=32h+r0, k-slice s: tile + half*4096B + (2s+h)*512B +
// r0*16B -> contiguous per 32-lane half; conflict-free.
// Blocks [0,PREP_KBLK): K. Rest: V.
// ---------------------------------------------------------------------------
__global__ __launch_bounds__(256)
void fa_prep(const float* __restrict__ kg, const float* __restrict__ vg,
             unsigned short* __restrict__ kb, unsigned short* __restrict__ vb)
{
    const int tid = threadIdx.x;
    const int bid = blockIdx.x;
    if (bid < PREP_KBLK) {
        // 4 x (16B chunk = 8 d-elems of one K row) per thread
        const int tcid = bid * 256 + tid;
        float4 a[4], b[4];
        size_t dsto[4];
        #pragma unroll
        for (int s = 0; s < 4; ++s) {
            const int cid = tcid + s * 262144;     // (head*S + kv)*8 + ch
            const int ch  = cid & 7;
            const int row = cid >> 3;              // head*S + kv
            const int kvt = row & 63;              // kv within tile
            const float4* sp = reinterpret_cast<const float4*>(kg + (size_t)row * D_DIM + ch * 8);
            a[s] = sp[0];
            b[s] = sp[1];
            // tile base (row - kvt)*64 shorts + fragment-major offset
            dsto[s] = (size_t)(row - kvt) * 64 + (kvt >> 5) * 2048 + ch * 256 + (kvt & 31) * 8;
        }
        #pragma unroll
        for (int s = 0; s < 4; ++s) {
            uint4 w;
            w.x = pack_bf16(a[s].x, a[s].y); w.y = pack_bf16(a[s].z, a[s].w);
            w.z = pack_bf16(b[s].x, b[s].y); w.w = pack_bf16(b[s].z, b[s].w);
            *reinterpret_cast<uint4*>(kb + dsto[s]) = w;
        }
    } else {
        // 4 x (64x64 V tile) per wave, grid-stride; lane = (kv-group, d-group)
        const int wvb  = (bid - PREP_KBLK) * 4 + (tid >> 6);
        const int lane = tid & 63;
        const int kg8  = lane >> 3;                // kv chunk (kv = kg8*8 + i)
        const int dg   = lane & 7;                 // d group  (d  = dg*8  + j)
        #pragma unroll 1
        for (int s = 0; s < 4; ++s) {
            const int wv = wvb + s * (PREP_VBLK * 4);         // head*32 + t
            const float* sp = vg + ((size_t)wv * TK + kg8 * 8) * D_DIM + dg * 8;
            float va[8][8];                        // [kv in group i][d in group j]
            #pragma unroll
            for (int i = 0; i < 8; ++i) {
                const float4* q4 = reinterpret_cast<const float4*>(sp + (size_t)i * D_DIM);
                float4 x = q4[0], y = q4[1];
                va[i][0] = x.x; va[i][1] = x.y; va[i][2] = x.z; va[i][3] = x.w;
                va[i][4] = y.x; va[i][5] = y.y; va[i][6] = y.z; va[i][7] = y.w;
            }
            unsigned short* db = vb + (size_t)wv * 4096;      // tile base (8 KB)
            #pragma unroll
            for (int j = 0; j < 8; ++j) {
                const int d = dg * 8 + j;
                uint4 w;   // shorts i=0..7 (kv&7 ascending) — contiguous 16B
                w.x = pack_bf16(va[0][j], va[1][j]);
                w.y = pack_bf16(va[2][j], va[3][j]);
                w.z = pack_bf16(va[4][j], va[5][j]);
                w.w = pack_bf16(va[6][j], va[7][j]);
                *reinterpret_cast<uint4*>(db + (d >> 5) * 2048 + kg8 * 256 + (d & 31) * 8) = w;
            }
        }
    }
}

// ---------------------------------------------------------------------------
// Main: flash fwd, S^T formulation, 32x32x16 MFMA, P in registers.
// One 128-q tile per block (idx = 15 - blockIdx.y); wave owns 32 q.
// LDS = 2*8K (K dbuf) + 2*8K (V dbuf) = 32 KB -> 4 blocks/CU.
// ---------------------------------------------------------------------------
__global__ __launch_bounds__(256, 4)
void fa_fwd(const float* __restrict__ qg,
            const unsigned short* __restrict__ kb,
            const unsigned short* __restrict__ vb,
            float* __restrict__ og)
{
    const int head = blockIdx.x;           // fast dim -> XCD spread
    const int idx  = 15 - (int)blockIdx.y; // big tiles dispatch first
    const int q0   = idx * 128;
    const int tid  = threadIdx.x;
    const int wave = tid >> 6;
    const int lane = tid & 63;
    const int r0   = lane & 31;            // row/col-in-32 index
    const int h    = lane >> 5;            // half: lane<32 / lane>=32

    __shared__ unsigned short Kl[2][TK * D_DIM];   // fragment-major K tiles
    __shared__ unsigned short Vt[2][TK * D_DIM];   // fragment-major V^T tiles

    const size_t hoff = (size_t)head * S_LEN * D_DIM;
    const unsigned short* kbh = kb + hoff;
    const unsigned short* vbh = vb + hoff;
    float* __restrict__ ogh = og + hoff;

    const int sgo  = wave * 512 + lane * 8;    // staging src offset (shorts)
    char* klds = (char*)&Kl[0][0];
    char* vlds = (char*)&Vt[0][0];
    char* kw   = klds + wave * 1024;           // wave-uniform stage dest (buf 0)
    char* vw   = vlds + wave * 1024;

    // fragment read offset: lane L=32h+r0, k-slice s ->
    //   tile + half*4096 + (2s+h)*512 + r0*16   (contiguous per 32-lane half)
    const int fro = r0 * 16 + h * 512;

    const int T  = 2 * idx + 1;                // last kv-tile
    const int td = 2 * idx + (wave >> 1);      // this wave's diagonal tile

    const float QSC = 0.18033688011112042f;    // 1/8 * log2(e)

    // ---- Q fragments (B operand): col n=q=lane&31 (+32*wave), k=8h+j per 16-slice
    bf16x8 qf[4];
    {
        const int q = q0 + 32 * wave + r0;
        const float* qp = qg + hoff + (size_t)q * D_DIM;
        #pragma unroll
        for (int s = 0; s < 4; ++s) {
            const float* p = qp + 16 * s + 8 * h;
            float4 a = reinterpret_cast<const float4*>(p)[0];
            float4 b = reinterpret_cast<const float4*>(p)[1];
            unsigned int u0 = pack_bf16(a.x * QSC, a.y * QSC);
            unsigned int u1 = pack_bf16(a.z * QSC, a.w * QSC);
            unsigned int u2 = pack_bf16(b.x * QSC, b.y * QSC);
            unsigned int u3 = pack_bf16(b.z * QSC, b.w * QSC);
            qf[s][0] = (short)(u0 & 0xFFFF); qf[s][1] = (short)(u0 >> 16);
            qf[s][2] = (short)(u1 & 0xFFFF); qf[s][3] = (short)(u1 >> 16);
            qf[s][4] = (short)(u2 & 0xFFFF); qf[s][5] = (short)(u2 >> 16);
            qf[s][6] = (short)(u3 & 0xFFFF); qf[s][7] = (short)(u3 >> 16);
        }
    }

    float l_i = 0.f;
    f32x16 mc, oacc0, oacc1;
    #pragma unroll
    for (int g = 0; g < 16; ++g) { mc[g] = MINIT; oacc0[g] = 0.f; oacc1[g] = 0.f; }

    // ---- prologue: stage tile 0 into buf 0
    {
        const unsigned short* ks = kbh + sgo;
        const unsigned short* vs = vbh + sgo;
        stage16(ks,        kw);
        stage16(ks + 2048, kw + 4096);
        stage16(vs,        vw);
        stage16(vs + 2048, vw + 4096);
    }
    __syncthreads();

    int cur = 0;
    for (int t = 0; t <= T; ++t) {
        if (t < T) {
            const unsigned short* ks = kbh + (size_t)(t + 1) * 4096 + sgo;
            const unsigned short* vs = vbh + (size_t)(t + 1) * 4096 + sgo;
            const int nb = (cur ^ 1) * 8192;
            stage16(ks,        kw + nb);
            stage16(ks + 2048, kw + nb + 4096);
            stage16(vs,        vw + nb);
            stage16(vs + 2048, vw + nb + 4096);
        }

        if (t <= td) {   // wave-uniform; dead waves skip compute, still barrier
            const char* kt = klds + cur * 8192 + fro;
            const char* vt = vlds + cur * 8192 + fro;

            // ---- S^T = K·Q^T + (-m): s0 = kv rows 0..31, s1 = 32..63 of tile
            f32x16 s0, s1;
            __builtin_amdgcn_s_setprio(1);
            {
                bf16x8 k0 = *reinterpret_cast<const bf16x8*>(kt);
                bf16x8 k1 = *reinterpret_cast<const bf16x8*>(kt + 4096);
                s0 = __builtin_amdgcn_mfma_f32_32x32x16_bf16(k0, qf[0], mc, 0, 0, 0);
                s1 = __builtin_amdgcn_mfma_f32_32x32x16_bf16(k1, qf[0], mc, 0, 0, 0);
            }
            #pragma unroll
            for (int s = 1; s < 4; ++s) {
                bf16x8 k0 = *reinterpret_cast<const bf16x8*>(kt + s * 1024);
                bf16x8 k1 = *reinterpret_cast<const bf16x8*>(kt + 4096 + s * 1024);
                s0 = __builtin_amdgcn_mfma_f32_32x32x16_bf16(k0, qf[s], s0, 0, 0, 0);
                s1 = __builtin_amdgcn_mfma_f32_32x32x16_bf16(k1, qf[s], s1, 0, 0, 0);
            }
            __builtin_amdgcn_s_setprio(0);

            // ---- causal mask at this wave's diagonal tile.
            // row(reg) = (reg&3)+8*(reg>>2)+4h (+32 for s1); col = r0.
            if (t == td) {
                if ((wave & 1) == 0) {
                    #pragma unroll
                    for (int g = 0; g < 16; ++g) {
                        const int rl = (g & 3) + 8 * (g >> 2) + 4 * h;
                        if (rl > r0) s0[g] = MASKV;
                        s1[g] = MASKV;                   // rows 32..63 all > col
                    }
                } else {
                    #pragma unroll
                    for (int g = 0; g < 16; ++g) {
                        const int rl = (g & 3) + 8 * (g >> 2) + 4 * h;
                        if (rl > r0) s1[g] = MASKV;      // s0 rows never masked
                    }
                }
            }

            // ---- softmax (relative domain, defer-max); column pair via permlane
            float t0 = fmax3(s0[0],  s0[1],  s0[2]);
            float t1 = fmax3(s0[3],  s0[4],  s0[5]);
            float t2 = fmax3(s0[6],  s0[7],  s0[8]);
            float t3 = fmax3(s0[9],  s0[10], s0[11]);
            float t4 = fmax3(s0[12], s0[13], s0[14]);
            float t5 = fmax3(s0[15], s1[0],  s1[1]);
            float t6 = fmax3(s1[2],  s1[3],  s1[4]);
            float t7 = fmax3(s1[5],  s1[6],  s1[7]);
            float t8 = fmax3(s1[8],  s1[9],  s1[10]);
            float t9 = fmax3(s1[11], s1[12], s1[13]);
            float u0 = fmax3(t0, t1, t2);
            float u1 = fmax3(t3, t4, t5);
            float u2 = fmax3(t6, t7, t8);
            float u3 = fmax3(t9, s1[14], s1[15]);
            float rm = fmaxf(fmax3(u0, u1, u2), u3);
            { float a, b; plswapf(rm, a, b); rm = fmaxf(a, b); }

            if (__any(rm > DEFER_THR)) {
                float mx    = fmaxf(rm, 0.f);
                float alpha = fast_exp2(-mx);
                l_i *= alpha;
                #pragma unroll
                for (int g = 0; g < 16; ++g) {
                    oacc0[g] *= alpha; oacc1[g] *= alpha;
                    s0[g] -= mx; s1[g] -= mx;
                    mc[g] -= mx;
                }
            }

            float ea[16], eb[16];
            float rs = 0.f;
            #pragma unroll
            for (int g = 0; g < 16; ++g) {
                ea[g] = fast_exp2(s0[g]);
                eb[g] = fast_exp2(s1[g]);
            }
            #pragma unroll
            for (int g = 0; g < 16; ++g) rs += ea[g] + eb[g];
            { float a, b; plswapf(rs, a, b); l_i += a + b; }

            // ---- P -> B-fragments in-register: pack pairs, permlane32-swap.
            unsigned int pa[8], pb[8];
            #pragma unroll
            for (int k = 0; k < 8; ++k) {
                pa[k] = pack_bf16_fast(ea[2 * k], ea[2 * k + 1]);
                pb[k] = pack_bf16_fast(eb[2 * k], eb[2 * k + 1]);
            }
            plswap(pa[0], pa[2]); plswap(pa[1], pa[3]);
            plswap(pa[4], pa[6]); plswap(pa[5], pa[7]);
            plswap(pb[0], pb[2]); plswap(pb[1], pb[3]);
            plswap(pb[4], pb[6]); plswap(pb[5], pb[7]);
            union { unsigned int u[4]; bf16x8 v; } pf[4];
            pf[0].u[0] = pa[0]; pf[0].u[1] = pa[1]; pf[0].u[2] = pa[2]; pf[0].u[3] = pa[3];
            pf[1].u[0] = pa[4]; pf[1].u[1] = pa[5]; pf[1].u[2] = pa[6]; pf[1].u[3] = pa[7];
            pf[2].u[0] = pb[0]; pf[2].u[1] = pb[1]; pf[2].u[2] = pb[2]; pf[2].u[3] = pb[3];
            pf[3].u[0] = pb[4]; pf[3].u[1] = pb[5]; pf[3].u[2] = pb[6]; pf[3].u[3] = pb[7];

            // ---- O^T += V^T·P^T  (A = V^T frags from LDS, B = pf in regs)
            __builtin_amdgcn_s_setprio(1);
            #pragma unroll
            for (int s = 0; s < 4; ++s) {
                bf16x8 v0 = *reinterpret_cast<const bf16x8*>(vt + s * 1024);
                bf16x8 v1 = *reinterpret_cast<const bf16x8*>(vt + 4096 + s * 1024);
                oacc0 = __builtin_amdgcn_mfma_f32_32x32x16_bf16(v0, pf[s].v, oacc0, 0, 0, 0);
                oacc1 = __builtin_amdgcn_mfma_f32_32x32x16_bf16(v1, pf[s].v, oacc1, 0, 0, 0);
            }
            __builtin_amdgcn_s_setprio(0);
        }

        __syncthreads();   // drains vmcnt (next tile staged) + lgkmcnt
        cur ^= 1;
    }

    // ---- epilogue: lane owns col q = q0+32*wave+r0; rows d from C layout
    {
        const float inv = 1.0f / l_i;
        float* op = ogh + (size_t)(q0 + 32 * wave + r0) * D_DIM;
        #pragma unroll
        for (int a = 0; a < 4; ++a) {
            float4 o4;
            o4.x = oacc0[4 * a + 0] * inv;
            o4.y = oacc0[4 * a + 1] * inv;
            o4.z = oacc0[4 * a + 2] * inv;
            o4.w = oacc0[4 * a + 3] * inv;
            reinterpret_cast<float4*>(op + 8 * a + 4 * h)[0] = o4;
        }
        #pragma unroll
        for (int a = 0; a < 4; ++a) {
            float4 o4;
            o4.x = oacc1[4 * a + 0] * inv;
            o4.y = oacc1[4 * a + 1] * inv;
            o4.z = oacc1[4 * a + 2] * inv;
            o4.w = oacc1[4 * a + 3] * inv;
            reinterpret_cast<float4*>(op + 32 + 8 * a + 4 * h)[0] = o4;
        }
    }
}

// ---------------------------------------------------------------------------
// Fallback (R6 kernel, verbatim) — used only if ws_size < 32 MiB.
// ---------------------------------------------------------------------------
__global__ __launch_bounds__(256, 4)
void fa_fwd_fb(const float* __restrict__ qg,
               const float* __restrict__ kg,
               const float* __restrict__ vg,
               float* __restrict__ og)
{
    const int head = blockIdx.x;
    const int pr   = blockIdx.y;
    const int tid  = threadIdx.x;
    const int wave = tid >> 6;
    const int lane = tid & 63;
    const int m16  = lane & 15;
    const int quad = lane >> 4;

    __shared__ unsigned short Kl[TK][LSTR];
    __shared__ unsigned short Vt[D_DIM][LSTR];
    __shared__ unsigned short Pl[4][16][LSTR];

    const size_t hoff = (size_t)head * S_LEN * D_DIM;
    const float* kh = kg + hoff;
    const float* vh = vg + hoff;

    const int ksr = tid >> 2;
    const int ksc = (tid & 3) << 4;
    const int va  = lane >> 3;
    const int vb  = lane & 7;
    const int vrr = wave * 16 + 2 * vb;
    const int vcc = 8 * va;
    const float LOG2E = 1.4426950408889634f;

    for (int pass = 0; pass < 2; ++pass) {
        const int q0 = ((pass == 0) ? pr : (31 - pr)) * TK;

        bf16x8 qf[2];
        {
            const float* qp = qg + hoff + (size_t)(q0 + wave * 16 + m16) * D_DIM + quad * 8;
            #pragma unroll
            for (int c = 0; c < 2; ++c) {
                float4 a = reinterpret_cast<const float4*>(qp + c * 32)[0];
                float4 b = reinterpret_cast<const float4*>(qp + c * 32)[1];
                unsigned int u0 = pack_bf16(a.x * 0.125f, a.y * 0.125f);
                unsigned int u1 = pack_bf16(a.z * 0.125f, a.w * 0.125f);
                unsigned int u2 = pack_bf16(b.x * 0.125f, b.y * 0.125f);
                unsigned int u3 = pack_bf16(b.z * 0.125f, b.w * 0.125f);
                qf[c][0] = (short)(u0 & 0xFFFF); qf[c][1] = (short)(u0 >> 16);
                qf[c][2] = (short)(u1 & 0xFFFF); qf[c][3] = (short)(u1 >> 16);
                qf[c][4] = (short)(u2 & 0xFFFF); qf[c][5] = (short)(u2 >> 16);
                qf[c][6] = (short)(u3 & 0xFFFF); qf[c][7] = (short)(u3 >> 16);
            }
        }

        float m_i = MNEG, l_i = 0.f;
        f32x4 oacc[4];
        #pragma unroll
        for (int nc = 0; nc < 4; ++nc) oacc[nc] = (f32x4){0.f, 0.f, 0.f, 0.f};

        float4 kA, kB, kC, kD, vA, vB, vC, vD;
        {
            const float* kp = kh + (size_t)ksr * D_DIM + ksc;
            kA = reinterpret_cast<const float4*>(kp)[0];
            kB = reinterpret_cast<const float4*>(kp)[1];
            kC = reinterpret_cast<const float4*>(kp)[2];
            kD = reinterpret_cast<const float4*>(kp)[3];
            const float* vp = vh + (size_t)vrr * D_DIM + vcc;
            vA = reinterpret_cast<const float4*>(vp)[0];
            vB = reinterpret_cast<const float4*>(vp)[1];
            vC = reinterpret_cast<const float4*>(vp + D_DIM)[0];
            vD = reinterpret_cast<const float4*>(vp + D_DIM)[1];
        }

        for (int j0 = 0; j0 <= q0; j0 += TK) {
            __syncthreads();
            {
                uint4 w0, w1;
                w0.x = pack_bf16(kA.x, kA.y); w0.y = pack_bf16(kA.z, kA.w);
                w0.z = pack_bf16(kB.x, kB.y); w0.w = pack_bf16(kB.z, kB.w);
                w1.x = pack_bf16(kC.x, kC.y); w1.y = pack_bf16(kC.z, kC.w);
                w1.z = pack_bf16(kD.x, kD.y); w1.w = pack_bf16(kD.z, kD.w);
                *reinterpret_cast<uint4*>(&Kl[ksr][ksc])     = w0;
                *reinterpret_cast<uint4*>(&Kl[ksr][ksc + 8]) = w1;

                float r0[8] = {vA.x, vA.y, vA.z, vA.w, vB.x, vB.y, vB.z, vB.w};
                float r1[8] = {vC.x, vC.y, vC.z, vC.w, vD.x, vD.y, vD.z, vD.w};
                #pragma unroll
                for (int jj = 0; jj < 8; ++jj) {
                    int j = (jj + va) & 7;
                    *reinterpret_cast<unsigned int*>(&Vt[vcc + j][vrr]) = pack_bf16(r0[j], r1[j]);
                }
            }
            __syncthreads();

            if (j0 + TK <= q0) {
                const float* kp = kh + (size_t)(j0 + TK + ksr) * D_DIM + ksc;
                kA = reinterpret_cast<const float4*>(kp)[0];
                kB = reinterpret_cast<const float4*>(kp)[1];
                kC = reinterpret_cast<const float4*>(kp)[2];
                kD = reinterpret_cast<const float4*>(kp)[3];
                const float* vp = vh + (size_t)(j0 + TK + vrr) * D_DIM + vcc;
                vA = reinterpret_cast<const float4*>(vp)[0];
                vB = reinterpret_cast<const float4*>(vp)[1];
                vC = reinterpret_cast<const float4*>(vp + D_DIM)[0];
                vD = reinterpret_cast<const float4*>(vp + D_DIM)[1];
            }

            float sv[4][4];
            #pragma unroll
            for (int nt = 0; nt < 4; ++nt) {
                f32x4 acc = (f32x4){0.f, 0.f, 0.f, 0.f};
                bf16x8 kf0 = *reinterpret_cast<const bf16x8*>(&Kl[nt * 16 + m16][quad * 8]);
                bf16x8 kf1 = *reinterpret_cast<const bf16x8*>(&Kl[nt * 16 + m16][32 + quad * 8]);
                acc = __builtin_amdgcn_mfma_f32_16x16x32_bf16(kf0, qf[0], acc, 0, 0, 0);
                acc = __builtin_amdgcn_mfma_f32_16x16x32_bf16(kf1, qf[1], acc, 0, 0, 0);
                #pragma unroll
                for (int r = 0; r < 4; ++r) sv[nt][r] = acc[r];
            }

            if (j0 == q0) {
                #pragma unroll
                for (int nt = 0; nt < 4; ++nt)
                    #pragma unroll
                    for (int r = 0; r < 4; ++r)
                        if (nt * 16 + quad * 4 + r > wave * 16 + m16) sv[nt][r] = MNEG;
            }

            float a0 = fmaxf(fmaxf(sv[0][0], sv[0][1]), fmaxf(sv[0][2], sv[0][3]));
            float a1 = fmaxf(fmaxf(sv[1][0], sv[1][1]), fmaxf(sv[1][2], sv[1][3]));
            float a2 = fmaxf(fmaxf(sv[2][0], sv[2][1]), fmaxf(sv[2][2], sv[2][3]));
            float a3 = fmaxf(fmaxf(sv[3][0], sv[3][1]), fmaxf(sv[3][2], sv[3][3]));
            float rm = fmaxf(fmaxf(a0, a1), fmaxf(a2, a3));
            rm = fmaxf(rm, __shfl_xor(rm, 16, 64));
            rm = fmaxf(rm, __shfl_xor(rm, 32, 64));
            float mnew  = fmaxf(m_i, rm);
            float alpha = fast_exp2((m_i - mnew) * LOG2E);
            float msc   = mnew * LOG2E;
            m_i = mnew;

            float rs = 0.f;
            #pragma unroll
            for (int nt = 0; nt < 4; ++nt) {
                float e0 = fast_exp2(fmaf(sv[nt][0], LOG2E, -msc));
                float e1 = fast_exp2(fmaf(sv[nt][1], LOG2E, -msc));
                float e2 = fast_exp2(fmaf(sv[nt][2], LOG2E, -msc));
                float e3 = fast_exp2(fmaf(sv[nt][3], LOG2E, -msc));
                rs += (e0 + e1) + (e2 + e3);
                uint2 pw;
                pw.x = pack_bf16(e0, e1);
                pw.y = pack_bf16(e2, e3);
                *reinterpret_cast<uint2*>(&Pl[wave][m16][nt * 16 + quad * 4]) = pw;
            }
            rs += __shfl_xor(rs, 16, 64);
            rs += __shfl_xor(rs, 32, 64);
            l_i = fmaf(alpha, l_i, rs);

            #pragma unroll
            for (int nc = 0; nc < 4; ++nc)
                #pragma unroll
                for (int r = 0; r < 4; ++r)
                    oacc[nc][r] *= alpha;

            asm volatile("s_waitcnt lgkmcnt(0)" ::: "memory");

            bf16x8 pf0 = *reinterpret_cast<const bf16x8*>(&Pl[wave][m16][quad * 8]);
            bf16x8 pf1 = *reinterpret_cast<const bf16x8*>(&Pl[wave][m16][32 + quad * 8]);
            #pragma unroll
            for (int nc = 0; nc < 4; ++nc) {
                bf16x8 vf0 = *reinterpret_cast<const bf16x8*>(&Vt[nc * 16 + m16][quad * 8]);
                bf16x8 vf1 = *reinterpret_cast<const bf16x8*>(&Vt[nc * 16 + m16][32 + quad * 8]);
                oacc[nc] = __builtin_amdgcn_mfma_f32_16x16x32_bf16(vf0, pf0, oacc[nc], 0, 0, 0);
                oacc[nc] = __builtin_amdgcn_mfma_f32_16x16x32_bf16(vf1, pf1, oacc[nc], 0, 0, 0);
            }
        }

        float inv = 1.0f / l_i;
        float* op = og + hoff + (size_t)(q0 + wave * 16 + m16) * D_DIM;
        #pragma unroll
        for (int nc = 0; nc < 4; ++nc) {
            float4 o4;
            o4.x = oacc[nc][0] * inv;
            o4.y = oacc[nc][1] * inv;
            o4.z = oacc[nc][2] * inv;
            o4.w = oacc[nc][3] * inv;
            reinterpret_cast<float4*>(op + nc * 16 + quad * 4)[0] = o4;
        }
    }
}

extern "C" void kernel_launch(void* const* d_in, const int* in_sizes, int n_in,
                              void* d_out, int out_size, void* d_ws, size_t ws_size,
                              hipStream_t stream) {
    const float* q = (const float*)d_in[0];
    const float* k = (const float*)d_in[1];
    const float* v = (const float*)d_in[2];
    float* o = (float*)d_out;
    const size_t kvShorts = (size_t)NHEAD * S_LEN * D_DIM;           // 8.39M
    const size_t wsNeed   = 2 * kvShorts * sizeof(unsigned short);   // 32 MiB
    if (d_ws != nullptr && ws_size >= wsNeed) {
        unsigned short* kbp = (unsigned short*)d_ws;
        unsigned short* vbp = kbp + kvShorts;
        fa_prep<<<PREP_KBLK + PREP_VBLK, 256, 0, stream>>>(k, v, kbp, vbp);
        dim3 grid(NHEAD, 16);
        fa_fwd<<<grid, 256, 0, stream>>>(q, kbp, vbp, o);
    } else {
        dim3 grid(NHEAD, 16);
        fa_fwd_fb<<<grid, 256, 0, stream>>>(q, k, v, o);
    }
}